// Round 1
// baseline (2579.664 us; speedup 1.0000x reference)
//
#include <hip/hip_runtime.h>
#include <stdint.h>

// ---------- common types / helpers ----------
typedef __attribute__((ext_vector_type(8))) short bf8;   // 8 x bf16 (4 VGPRs)
typedef __attribute__((ext_vector_type(4))) float f4;    // MFMA accumulator

__device__ __forceinline__ float bf2f(uint16_t u) {
  union { unsigned i; float f; } v; v.i = ((unsigned)u) << 16; return v.f;
}
__device__ __forceinline__ uint16_t f2bf(float f) {
  union { float f; unsigned i; } v; v.f = f;
  unsigned r = v.i + 0x7fffu + ((v.i >> 16) & 1u);   // RTNE
  return (uint16_t)(r >> 16);
}
__device__ __forceinline__ bf8 cvt8(float4 a, float4 b) {
  bf8 r;
  r[0]=(short)f2bf(a.x); r[1]=(short)f2bf(a.y); r[2]=(short)f2bf(a.z); r[3]=(short)f2bf(a.w);
  r[4]=(short)f2bf(b.x); r[5]=(short)f2bf(b.y); r[6]=(short)f2bf(b.z); r[7]=(short)f2bf(b.w);
  return r;
}

// ---------- GEMM: C[M,N] = A[M,K] * B[N,K]^T ----------
// 128x128 tile, BK=32, 4 waves (2x2 of 64x64), mfma_f32_16x16x32_bf16.
// A source: f32 (converted) or bf16. B source: f32 (converted). C: bf16 or f32.
// LDS tiles padded to stride 40 elems -> conflict-free ds_read_b128.
template<bool AF32, bool OF32>
__global__ __launch_bounds__(256)
void eagle3_gemm(const void* __restrict__ Ap, const float* __restrict__ Bp,
                 void* __restrict__ Cp, int M, int N, int K,
                 int lda, int ldb, int ldc)
{
  __shared__ __align__(16) uint16_t As[128 * 40];
  __shared__ __align__(16) uint16_t Bs[128 * 40];
  const int tid = threadIdx.x;
  const int lane = tid & 63;
  const int tl = lane & 15, g = lane >> 4;
  const int m0 = blockIdx.y * 128, n0 = blockIdx.x * 128;
  const int w = tid >> 6;
  const int wr = (w >> 1) * 64, wc = (w & 1) * 64;
  const int sr = tid >> 1;            // staging row 0..127 (2 threads/row)
  const int sc = (tid & 1) * 16;      // staging col 0 or 16

  f4 acc[4][4] = {};

  for (int k0 = 0; k0 < K; k0 += 32) {
    // -- load next tiles to registers (no LDS touch yet) --
    bf8 a0, a1, b0, b1;
    if (AF32) {
      const float* sa = (const float*)Ap + (size_t)(m0 + sr) * lda + k0 + sc;
      a0 = cvt8(*(const float4*)(sa + 0), *(const float4*)(sa + 4));
      a1 = cvt8(*(const float4*)(sa + 8), *(const float4*)(sa + 12));
    } else {
      const uint16_t* sa = (const uint16_t*)Ap + (size_t)(m0 + sr) * lda + k0 + sc;
      a0 = *(const bf8*)sa;
      a1 = *(const bf8*)(sa + 8);
    }
    {
      const float* sb = Bp + (size_t)(n0 + sr) * ldb + k0 + sc;
      b0 = cvt8(*(const float4*)(sb + 0), *(const float4*)(sb + 4));
      b1 = cvt8(*(const float4*)(sb + 8), *(const float4*)(sb + 12));
    }
    __syncthreads();                       // previous iteration's reads done
    *(bf8*)&As[sr * 40 + sc]     = a0;
    *(bf8*)&As[sr * 40 + sc + 8] = a1;
    *(bf8*)&Bs[sr * 40 + sc]     = b0;
    *(bf8*)&Bs[sr * 40 + sc + 8] = b1;
    __syncthreads();                       // tiles visible

    bf8 af[4], bf_[4];
    #pragma unroll
    for (int i = 0; i < 4; ++i) {
      af[i]  = *(const bf8*)&As[(wr + i * 16 + tl) * 40 + g * 8];
      bf_[i] = *(const bf8*)&Bs[(wc + i * 16 + tl) * 40 + g * 8];
    }
    #pragma unroll
    for (int mi = 0; mi < 4; ++mi)
      #pragma unroll
      for (int ni = 0; ni < 4; ++ni)
        acc[mi][ni] = __builtin_amdgcn_mfma_f32_16x16x32_bf16(af[mi], bf_[ni], acc[mi][ni], 0, 0, 0);
  }

  // epilogue: C/D layout col=lane&15, row=(lane>>4)*4+reg
  #pragma unroll
  for (int mi = 0; mi < 4; ++mi) {
    #pragma unroll
    for (int r = 0; r < 4; ++r) {
      const int row = m0 + wr + mi * 16 + g * 4 + r;
      #pragma unroll
      for (int ni = 0; ni < 4; ++ni) {
        const int col = n0 + wc + ni * 16 + tl;
        const float v = acc[mi][ni][r];
        if (OF32) ((float*)Cp)[(size_t)row * ldc + col] = v;
        else      ((uint16_t*)Cp)[(size_t)row * ldc + col] = f2bf(v);
      }
    }
  }
}

// ---------- RoPE (in-place on bf16, pairs (d, d+64)) ----------
__global__ __launch_bounds__(256)
void eagle3_rope(uint16_t* __restrict__ x, const float* __restrict__ cs,
                 const float* __restrict__ sn, int nh, int rowlen, int total)
{
  int id = blockIdx.x * 256 + threadIdx.x;
  if (id >= total) return;
  int d = id & 63;
  int t = id >> 6;
  int head = t & (nh - 1);   // nh is power of 2
  int row = t / nh;
  int s = row & 2047;        // row = b*2048 + s
  size_t base = (size_t)row * rowlen + head * 128;
  float c = cs[s * 128 + d], si = sn[s * 128 + d];   // cos/sin[d] == cos/sin[d+64]
  float x1 = bf2f(x[base + d]), x2 = bf2f(x[base + d + 64]);
  x[base + d]      = f2bf(x1 * c - x2 * si);
  x[base + d + 64] = f2bf(x2 * c + x1 * si);
}

// ---------- causal GQA flash attention ----------
// grid (S/64, NQ, B); 4 waves, each wave owns 16 Q rows; KV tile = 32.
// K tile LDS: linear [32][128] holding XOR-swizzled chunks (chunk ^= row&7).
// V tile LDS: transposed [128][40] (pad 40 -> conflict-free b128 reads).
__global__ __launch_bounds__(256)
void eagle3_flash(const uint16_t* __restrict__ Q, const uint16_t* __restrict__ Kt,
                  const uint16_t* __restrict__ Vt, uint16_t* __restrict__ O)
{
  __shared__ __align__(16) uint16_t Ks[32 * 128];
  __shared__ __align__(16) uint16_t Vts[128 * 40];
  __shared__ __align__(16) uint16_t Pl[4 * 16 * 40];

  const int tid = threadIdx.x, lane = tid & 63, w = tid >> 6;
  const int tl = lane & 15, g = lane >> 4;
  const int qt = blockIdx.x, hq = blockIdx.y, b = blockIdx.z;
  const int hkv = hq >> 2;
  const int qrow0 = qt * 64 + w * 16;

  // Q fragments (A-operand): row = tl, k = kb*32 + g*8
  bf8 qf[4];
  {
    const uint16_t* qp = Q + ((size_t)(b * 2048 + qrow0 + tl)) * 4096 + hq * 128 + g * 8;
    #pragma unroll
    for (int kb = 0; kb < 4; ++kb) qf[kb] = *(const bf8*)(qp + kb * 32);
  }

  f4 acc[8] = {};
  float rm[4] = {-3e38f, -3e38f, -3e38f, -3e38f};
  float rl[4] = {0.f, 0.f, 0.f, 0.f};

  const float scale = 0.08838834764831845f;   // 1/sqrt(128)
  const int ntb = 2 * qt + 2;

  for (int tb = 0; tb < ntb; ++tb) {
    const int t0 = tb * 32;

    // -- load K/V tile rows to regs (straight chunks) --
    bf8 kreg[2], vreg[2];
    #pragma unroll
    for (int i = 0; i < 2; ++i) {
      const int f = i * 256 + tid;
      const int r = f >> 4, c8 = f & 15;
      const size_t gb = ((size_t)(b * 2048 + t0 + r)) * 1024 + hkv * 128;
      kreg[i] = *(const bf8*)(Kt + gb + c8 * 8);
      vreg[i] = *(const bf8*)(Vt + gb + c8 * 8);
    }
    __syncthreads();   // previous iteration's LDS reads done
    #pragma unroll
    for (int i = 0; i < 2; ++i) {
      const int f = i * 256 + tid;
      const int r = f >> 4, c8 = f & 15;
      *(bf8*)&Ks[r * 128 + ((c8 ^ (r & 7)) * 8)] = kreg[i];   // swizzled store
      #pragma unroll
      for (int j = 0; j < 8; ++j)
        Vts[(c8 * 8 + j) * 40 + r] = (uint16_t)vreg[i][j];    // transpose
    }
    __syncthreads();

    // -- QK^T: S(16x32) = Q(16x128) x K^T, two 16-col fragments --
    f4 s0 = {}, s1 = {};
    #pragma unroll
    for (int kb = 0; kb < 4; ++kb) {
      const int swz = ((kb * 4 + g) ^ (tl & 7)) * 8;
      bf8 k0f = *(const bf8*)&Ks[tl * 128 + swz];
      bf8 k1f = *(const bf8*)&Ks[(16 + tl) * 128 + swz];
      s0 = __builtin_amdgcn_mfma_f32_16x16x32_bf16(qf[kb], k0f, s0, 0, 0, 0);
      s1 = __builtin_amdgcn_mfma_f32_16x16x32_bf16(qf[kb], k1f, s1, 0, 0, 0);
    }

    // -- online softmax (rows spread over 16-lane groups; cols = tl) --
    float p0[4], p1[4];
    #pragma unroll
    for (int r = 0; r < 4; ++r) {
      const int qg = qrow0 + g * 4 + r;
      float v0 = s0[r] * scale, v1 = s1[r] * scale;
      if (t0 + tl > qg)      v0 = -1e30f;
      if (t0 + 16 + tl > qg) v1 = -1e30f;
      float mx = fmaxf(v0, v1);
      mx = fmaxf(mx, __shfl_xor(mx, 1));
      mx = fmaxf(mx, __shfl_xor(mx, 2));
      mx = fmaxf(mx, __shfl_xor(mx, 4));
      mx = fmaxf(mx, __shfl_xor(mx, 8));
      const float mnew = fmaxf(rm[r], mx);
      const float corr = __expf(rm[r] - mnew);
      const float e0 = __expf(v0 - mnew), e1 = __expf(v1 - mnew);
      float sum = e0 + e1;
      sum += __shfl_xor(sum, 1);
      sum += __shfl_xor(sum, 2);
      sum += __shfl_xor(sum, 4);
      sum += __shfl_xor(sum, 8);
      rl[r] = rl[r] * corr + sum;
      rm[r] = mnew;
      #pragma unroll
      for (int df = 0; df < 8; ++df) acc[df][r] *= corr;
      p0[r] = e0; p1[r] = e1;
    }

    // -- P -> LDS (per-wave region), re-read as A-fragment --
    uint16_t* Pw = &Pl[w * 16 * 40];
    #pragma unroll
    for (int r = 0; r < 4; ++r) {
      Pw[(g * 4 + r) * 40 + tl]      = f2bf(p0[r]);
      Pw[(g * 4 + r) * 40 + 16 + tl] = f2bf(p1[r]);
    }
    bf8 pf = *(const bf8*)&Pw[tl * 40 + g * 8];   // same-wave RAW: in-order DS

    // -- PV: acc(16x128) += P(16x32) x V(32x128) --
    #pragma unroll
    for (int df = 0; df < 8; ++df) {
      bf8 vf = *(const bf8*)&Vts[(df * 16 + tl) * 40 + g * 8];
      acc[df] = __builtin_amdgcn_mfma_f32_16x16x32_bf16(pf, vf, acc[df], 0, 0, 0);
    }
    __syncthreads();
  }

  // -- normalize + store ctx[b, q, hq*128 + d] --
  #pragma unroll
  for (int r = 0; r < 4; ++r) {
    const float inv = 1.0f / rl[r];
    const size_t ob = ((size_t)(b * 2048 + qrow0 + g * 4 + r)) * 4096 + hq * 128 + tl;
    #pragma unroll
    for (int df = 0; df < 8; ++df)
      O[ob + df * 16] = f2bf(acc[df][r] * inv);
  }
}

// ---------- launch ----------
extern "C" void kernel_launch(void* const* d_in, const int* in_sizes, int n_in,
                              void* d_out, int out_size, void* d_ws, size_t ws_size,
                              hipStream_t stream) {
  const float* hs   = (const float*)d_in[0];
  // d_in[1] = attention_mask (exactly causal; implemented via predicate)
  const float* cosT = (const float*)d_in[2];
  const float* sinT = (const float*)d_in[3];
  const float* Wq   = (const float*)d_in[4];
  const float* Wk   = (const float*)d_in[5];
  const float* Wv   = (const float*)d_in[6];
  const float* Wo   = (const float*)d_in[7];

  char* ws = (char*)d_ws;
  uint16_t* qb   = (uint16_t*)(ws);                 // [4096, 4096] bf16
  uint16_t* kbuf = (uint16_t*)(ws + 33554432);      // [4096, 1024] bf16
  uint16_t* vbuf = (uint16_t*)(ws + 41943040);      // [4096, 1024] bf16
  uint16_t* ctx  = (uint16_t*)(ws + 50331648);      // [4096, 4096] bf16
  // total ws used: 83,886,080 bytes

  const dim3 blk(256);

  // QKV projections: C = hs * W^T
  eagle3_gemm<true, false><<<dim3(32, 32), blk, 0, stream>>>(
      (const void*)hs, Wq, (void*)qb, 4096, 4096, 8192, 8192, 8192, 4096);
  eagle3_gemm<true, false><<<dim3(8, 32), blk, 0, stream>>>(
      (const void*)hs, Wk, (void*)kbuf, 4096, 1024, 8192, 8192, 8192, 1024);
  eagle3_gemm<true, false><<<dim3(8, 32), blk, 0, stream>>>(
      (const void*)hs, Wv, (void*)vbuf, 4096, 1024, 8192, 8192, 8192, 1024);

  // RoPE in-place (Q: 32 heads, K: 8 heads)
  eagle3_rope<<<dim3(32768), blk, 0, stream>>>(qb, cosT, sinT, 32, 4096, 8388608);
  eagle3_rope<<<dim3(8192), blk, 0, stream>>>(kbuf, cosT, sinT, 8, 1024, 2097152);

  // causal GQA flash attention -> ctx
  eagle3_flash<<<dim3(32, 32, 2), blk, 0, stream>>>(qb, kbuf, vbuf, ctx);

  // output projection: out = ctx * Wo^T (f32 out)
  eagle3_gemm<false, true><<<dim3(32, 32), blk, 0, stream>>>(
      (const void*)ctx, Wo, d_out, 4096, 4096, 4096, 4096, 4096, 4096);
}

// Round 3
// 2375.949 us; speedup vs baseline: 1.0857x; 1.0857x over previous
//
#include <hip/hip_runtime.h>
#include <stdint.h>

// ---------- common types / helpers ----------
typedef __attribute__((ext_vector_type(8))) short bf8;   // 8 x bf16 (4 VGPRs)
typedef __attribute__((ext_vector_type(4))) float f4;    // MFMA accumulator

__device__ __forceinline__ float bf2f(uint16_t u) {
  union { unsigned i; float f; } v; v.i = ((unsigned)u) << 16; return v.f;
}
__device__ __forceinline__ uint16_t f2bf(float f) {
  union { float f; unsigned i; } v; v.f = f;
  unsigned r = v.i + 0x7fffu + ((v.i >> 16) & 1u);   // RTNE
  return (uint16_t)(r >> 16);
}
__device__ __forceinline__ bf8 cvt8(float4 a, float4 b) {
  bf8 r;
  r[0]=(short)f2bf(a.x); r[1]=(short)f2bf(a.y); r[2]=(short)f2bf(a.z); r[3]=(short)f2bf(a.w);
  r[4]=(short)f2bf(b.x); r[5]=(short)f2bf(b.y); r[6]=(short)f2bf(b.z); r[7]=(short)f2bf(b.w);
  return r;
}

// async global->LDS, 16B per lane, wave-uniform LDS base + lane*16
__device__ __forceinline__ void gload_lds16(const void* g, void* l) {
  __builtin_amdgcn_global_load_lds(
      (const __attribute__((address_space(1))) uint32_t*)(uintptr_t)g,
      (__attribute__((address_space(3))) uint32_t*)(uint32_t)(uintptr_t)l,
      16, 0, 0);
}

// ---------- f32 -> bf16 bulk convert ----------
__global__ __launch_bounds__(256)
void eagle3_cvt(const float* __restrict__ src, uint16_t* __restrict__ dst, int n8)
{
  int i = blockIdx.x * 256 + threadIdx.x;
  const int stride = gridDim.x * 256;
  for (; i < n8; i += stride) {
    const float4 a = ((const float4*)src)[i * 2];
    const float4 b = ((const float4*)src)[i * 2 + 1];
    ((bf8*)dst)[i] = cvt8(a, b);
  }
}

// ---------- GEMM: C[M,N] = A[M,K] * B[N,K]^T ----------
// 128x128 tile, BK=32, 4 waves (2x2 of 64x64), mfma_f32_16x16x32_bf16.
// B (bf16) staged via global_load_lds w/ XOR chunk swizzle (c ^= (row>>1)&3),
// swizzle applied to the per-lane GLOBAL source addr, LDS stays linear; the
// fragment read applies the same XOR -> cancels (both-sides-or-neither rule).
// A: f32 reg-cvt staged into padded LDS (AF32) or bf16 via global_load_lds.
template<bool AF32, bool OF32>
__global__ __launch_bounds__(256)
void eagle3_gemm2(const void* __restrict__ Ap, const uint16_t* __restrict__ Bp,
                  void* __restrict__ Cp, int K, int lda, int ldb, int ldc)
{
  constexpr int ALD = AF32 ? 40 : 32;
  __shared__ __align__(16) uint16_t As[128 * ALD];
  __shared__ __align__(16) uint16_t Bs[128 * 32];

  // XCD-bijective block swizzle (nwg % 8 == 0 for all our grids)
  const int nwg = gridDim.x * gridDim.y;
  const int bid = blockIdx.y * gridDim.x + blockIdx.x;
  const int qq = nwg >> 3;
  const int sw = (bid & 7) * qq + (bid >> 3);
  const int bx = sw % gridDim.x, by = sw / gridDim.x;
  const int m0 = by * 128, n0 = bx * 128;

  const int tid = threadIdx.x, lane = tid & 63, w = tid >> 6;
  const int tl = lane & 15, g = lane >> 4;
  const int wr = (w >> 1) * 64, wc = (w & 1) * 64;

  f4 acc[4][4] = {};

  for (int k0 = 0; k0 < K; k0 += 32) {
    bf8 a0, a1;
    const int sr = tid >> 1, sc2 = (tid & 1) * 16;
    if constexpr (AF32) {
      const float* sa = (const float*)Ap + (size_t)(m0 + sr) * lda + k0 + sc2;
      a0 = cvt8(*(const float4*)(sa),     *(const float4*)(sa + 4));
      a1 = cvt8(*(const float4*)(sa + 8), *(const float4*)(sa + 12));
    }
    __syncthreads();                        // prev iteration's frag reads done
    if constexpr (AF32) {
      *(bf8*)&As[sr * 40 + sc2]     = a0;
      *(bf8*)&As[sr * 40 + sc2 + 8] = a1;
    } else {
      #pragma unroll
      for (int i = 0; i < 2; ++i) {
        const int o = (w * 2 + i) * 1024 + lane * 16;   // byte offset in 8KB tile
        const int r = o >> 6;
        const int u = (((o >> 4) & 3) ^ ((r >> 1) & 3)) * 8;
        gload_lds16((const uint16_t*)Ap + (size_t)(m0 + r) * lda + k0 + u,
                    &As[(w * 2 + i) * 512]);
      }
    }
    #pragma unroll
    for (int i = 0; i < 2; ++i) {
      const int o = (w * 2 + i) * 1024 + lane * 16;
      const int r = o >> 6;
      const int u = (((o >> 4) & 3) ^ ((r >> 1) & 3)) * 8;
      gload_lds16(Bp + (size_t)(n0 + r) * ldb + k0 + u, &Bs[(w * 2 + i) * 512]);
    }
    __syncthreads();                        // drains vmcnt + lgkm -> tiles visible

    bf8 af[4], bf_[4];
    #pragma unroll
    for (int i = 0; i < 4; ++i) {
      const int ar = wr + i * 16 + tl;
      const int br = wc + i * 16 + tl;
      if constexpr (AF32) af[i] = *(const bf8*)&As[ar * 40 + g * 8];
      else                af[i] = *(const bf8*)&As[ar * 32 + ((g ^ ((ar >> 1) & 3)) * 8)];
      bf_[i] = *(const bf8*)&Bs[br * 32 + ((g ^ ((br >> 1) & 3)) * 8)];
    }
    #pragma unroll
    for (int mi = 0; mi < 4; ++mi)
      #pragma unroll
      for (int ni = 0; ni < 4; ++ni)
        acc[mi][ni] = __builtin_amdgcn_mfma_f32_16x16x32_bf16(af[mi], bf_[ni], acc[mi][ni], 0, 0, 0);
  }

  // epilogue: C/D layout col=lane&15, row=(lane>>4)*4+reg
  #pragma unroll
  for (int mi = 0; mi < 4; ++mi) {
    #pragma unroll
    for (int r = 0; r < 4; ++r) {
      const int row = m0 + wr + mi * 16 + g * 4 + r;
      #pragma unroll
      for (int ni = 0; ni < 4; ++ni) {
        const int col = n0 + wc + ni * 16 + tl;
        const float v = acc[mi][ni][r];
        if constexpr (OF32) ((float*)Cp)[(size_t)row * ldc + col] = v;
        else                ((uint16_t*)Cp)[(size_t)row * ldc + col] = f2bf(v);
      }
    }
  }
}

// ---------- RoPE (in-place on bf16, pairs (d, d+64)) ----------
__global__ __launch_bounds__(256)
void eagle3_rope(uint16_t* __restrict__ x, const float* __restrict__ cs,
                 const float* __restrict__ sn, int nh, int rowlen, int total)
{
  int id = blockIdx.x * 256 + threadIdx.x;
  if (id >= total) return;
  int d = id & 63;
  int t = id >> 6;
  int head = t & (nh - 1);
  int row = t / nh;
  int s = row & 2047;
  size_t base = (size_t)row * rowlen + head * 128;
  float c = cs[s * 128 + d], si = sn[s * 128 + d];
  float x1 = bf2f(x[base + d]), x2 = bf2f(x[base + d + 64]);
  x[base + d]      = f2bf(x1 * c - x2 * si);
  x[base + d + 64] = f2bf(x2 * c + x1 * si);
}

// ---------- V transpose: [b,t,h,d] -> [b,h,d,t] ----------
__global__ __launch_bounds__(256)
void eagle3_vtrans(const uint16_t* __restrict__ V, uint16_t* __restrict__ Vt)
{
  __shared__ uint16_t T[64 * 136];   // [t=64][d=128 + pad 8]
  const int tid = threadIdx.x;
  const int t0 = blockIdx.x * 64;
  const int bh = blockIdx.y;         // b*8 + h
  const int b = bh >> 3, h = bh & 7;
  {
    const int r = tid >> 2, c0 = (tid & 3) * 32;
    const uint16_t* src = V + (size_t)(b * 2048 + t0 + r) * 1024 + h * 128 + c0;
    #pragma unroll
    for (int j = 0; j < 4; ++j)
      *(bf8*)&T[r * 136 + c0 + j * 8] = *(const bf8*)(src + j * 8);
  }
  __syncthreads();
  {
    const int d = tid >> 1, tc = (tid & 1) * 32;
    uint16_t* dst = Vt + ((size_t)bh * 128 + d) * 2048 + t0 + tc;
    #pragma unroll
    for (int cc = 0; cc < 4; ++cc) {
      bf8 v;
      #pragma unroll
      for (int j = 0; j < 8; ++j) v[j] = T[(tc + cc * 8 + j) * 136 + d];
      *(bf8*)&dst[cc * 8] = v;
    }
  }
}

// ---------- causal GQA flash attention v2 (no K/V LDS, no barriers) ----------
// grid (S/64, NQ, B); 4 waves, each wave owns 16 Q rows; KV tile = 32.
// K fragments: contiguous 16B direct global reads (L1/L2-resident tile).
// V fragments: contiguous 16B reads from pre-transposed V^T [b,h,d,t].
__global__ __launch_bounds__(256)
void eagle3_flash2(const uint16_t* __restrict__ Q, const uint16_t* __restrict__ Kt,
                   const uint16_t* __restrict__ Vt, uint16_t* __restrict__ O)
{
  __shared__ __align__(16) uint16_t Pl[4 * 16 * 40];

  const int tid = threadIdx.x, lane = tid & 63, w = tid >> 6;
  const int tl = lane & 15, g = lane >> 4;
  const int qt = blockIdx.x, hq = blockIdx.y, b = blockIdx.z;
  const int hkv = hq >> 2;
  const int qrow0 = qt * 64 + w * 16;

  // Q fragments (A-operand): row = tl, k = kb*32 + g*8
  bf8 qf[4];
  {
    const uint16_t* qp = Q + ((size_t)(b * 2048 + qrow0 + tl)) * 4096 + hq * 128 + g * 8;
    #pragma unroll
    for (int kb = 0; kb < 4; ++kb) qf[kb] = *(const bf8*)(qp + kb * 32);
  }

  const uint16_t* Kbase = Kt + (size_t)b * 2048 * 1024 + hkv * 128;
  const uint16_t* Vbase = Vt + ((size_t)(b * 8 + hkv) * 128) * 2048;

  f4 acc[8] = {};
  float rm[4] = {-3e38f, -3e38f, -3e38f, -3e38f};
  float rl[4] = {0.f, 0.f, 0.f, 0.f};

  const float scale = 0.08838834764831845f;   // 1/sqrt(128)
  const int ntw = (qrow0 + 47) >> 5;          // per-wave causal bound

  for (int tb = 0; tb < ntw; ++tb) {
    const int t0 = tb * 32;

    // -- QK^T: S(16x32) = Q(16x128) x K^T, two 16-col halves --
    f4 s0 = {}, s1 = {};
    __builtin_amdgcn_s_setprio(1);
    #pragma unroll
    for (int kb = 0; kb < 4; ++kb) {
      bf8 k0f = *(const bf8*)(Kbase + (size_t)(t0 + tl) * 1024 + kb * 32 + g * 8);
      bf8 k1f = *(const bf8*)(Kbase + (size_t)(t0 + 16 + tl) * 1024 + kb * 32 + g * 8);
      s0 = __builtin_amdgcn_mfma_f32_16x16x32_bf16(qf[kb], k0f, s0, 0, 0, 0);
      s1 = __builtin_amdgcn_mfma_f32_16x16x32_bf16(qf[kb], k1f, s1, 0, 0, 0);
    }
    __builtin_amdgcn_s_setprio(0);

    // -- online softmax (rows in 16-lane groups; cols = tl / 16+tl) --
    float p0[4], p1[4];
    #pragma unroll
    for (int r = 0; r < 4; ++r) {
      const int qg = qrow0 + g * 4 + r;
      float v0 = s0[r] * scale, v1 = s1[r] * scale;
      if (t0 + tl > qg)      v0 = -1e30f;
      if (t0 + 16 + tl > qg) v1 = -1e30f;
      float mx = fmaxf(v0, v1);
      mx = fmaxf(mx, __shfl_xor(mx, 1));
      mx = fmaxf(mx, __shfl_xor(mx, 2));
      mx = fmaxf(mx, __shfl_xor(mx, 4));
      mx = fmaxf(mx, __shfl_xor(mx, 8));
      if (mx > rm[r]) {                       // rescale only when max grows
        const float corr = __expf(rm[r] - mx);
        rl[r] *= corr;
        #pragma unroll
        for (int df = 0; df < 8; ++df) acc[df][r] *= corr;
        rm[r] = mx;
      }
      const float e0 = __expf(v0 - rm[r]), e1 = __expf(v1 - rm[r]);
      float sum = e0 + e1;
      sum += __shfl_xor(sum, 1);
      sum += __shfl_xor(sum, 2);
      sum += __shfl_xor(sum, 4);
      sum += __shfl_xor(sum, 8);
      rl[r] += sum;
      p0[r] = e0; p1[r] = e1;
    }

    // -- P -> LDS (per-wave region), re-read as A-fragment --
    uint16_t* Pw = &Pl[w * 16 * 40];
    #pragma unroll
    for (int r = 0; r < 4; ++r) {
      Pw[(g * 4 + r) * 40 + tl]      = f2bf(p0[r]);
      Pw[(g * 4 + r) * 40 + 16 + tl] = f2bf(p1[r]);
    }
    bf8 pf = *(const bf8*)&Pw[tl * 40 + g * 8];   // same-wave RAW

    // -- PV: acc(16x128) += P(16x32) x V(32x128) --
    __builtin_amdgcn_s_setprio(1);
    #pragma unroll
    for (int df = 0; df < 8; ++df) {
      bf8 vf = *(const bf8*)(Vbase + (size_t)(df * 16 + tl) * 2048 + t0 + g * 8);
      acc[df] = __builtin_amdgcn_mfma_f32_16x16x32_bf16(pf, vf, acc[df], 0, 0, 0);
    }
    __builtin_amdgcn_s_setprio(0);
  }

  // -- normalize + store ctx[b, q, hq*128 + d] --
  #pragma unroll
  for (int r = 0; r < 4; ++r) {
    const float inv = 1.0f / rl[r];
    const size_t ob = ((size_t)(b * 2048 + qrow0 + g * 4 + r)) * 4096 + hq * 128 + tl;
    #pragma unroll
    for (int df = 0; df < 8; ++df)
      O[ob + df * 16] = f2bf(acc[df][r] * inv);
  }
}

// ---------- launch ----------
extern "C" void kernel_launch(void* const* d_in, const int* in_sizes, int n_in,
                              void* d_out, int out_size, void* d_ws, size_t ws_size,
                              hipStream_t stream) {
  const float* hs   = (const float*)d_in[0];
  const float* cosT = (const float*)d_in[2];
  const float* sinT = (const float*)d_in[3];
  const float* Wq   = (const float*)d_in[4];
  const float* Wk   = (const float*)d_in[5];
  const float* Wv   = (const float*)d_in[6];
  const float* Wo   = (const float*)d_in[7];

  // ---- workspace liveness plan (peak 83,886,080 B, proven in round 0/1) ----
  // [ 0M,32M) qb    [4096,4096] bf16   live: Q gemm -> flash
  // [32M,40M) kbuf  [4096,1024] bf16   live: K gemm -> flash
  // [40M,48M) vbuf  [4096,1024] bf16   live: V gemm -> vtrans
  // [48M,64M) wkbf  [1024,8192] bf16   live: cvt -> K gemm      (16 MB!)
  // [64M,80M) wvbf  [1024,8192] bf16   live: cvt -> V gemm      (16 MB!)
  // [72M,80M) vt    [16,128,2048] bf16 live: vtrans -> flash  (over wvbf tail)
  // [40M,72M) ctx   [4096,4096] bf16   live: flash -> Wo gemm (over dead bufs)
  // wqbf = d_out (64 MB exact)  live: cvt -> Q gemm (dead before final write)
  // wobf = qb                   live: cvt -> Wo gemm (after flash read of qb)
  char* ws = (char*)d_ws;
  uint16_t* qb   = (uint16_t*)(ws);
  uint16_t* kbuf = (uint16_t*)(ws + 33554432);
  uint16_t* vbuf = (uint16_t*)(ws + 41943040);
  uint16_t* wkbf = (uint16_t*)(ws + 50331648);
  uint16_t* wvbf = (uint16_t*)(ws + 67108864);
  uint16_t* vt   = (uint16_t*)(ws + 75497472);
  uint16_t* ctx  = (uint16_t*)(ws + 41943040);
  uint16_t* wqbf = (uint16_t*)d_out;
  uint16_t* wobf = qb;

  const dim3 blk(256);

  // 1) weight conversions
  eagle3_cvt<<<dim3(2048), blk, 0, stream>>>(Wq, wqbf, 4194304);
  eagle3_cvt<<<dim3(2048), blk, 0, stream>>>(Wk, wkbf, 1048576);
  eagle3_cvt<<<dim3(2048), blk, 0, stream>>>(Wv, wvbf, 1048576);

  // 2) QKV projections (A = hs f32 in-kernel cvt, B = bf16 via global_load_lds)
  eagle3_gemm2<true, false><<<dim3(32, 32), blk, 0, stream>>>(
      (const void*)hs, wqbf, (void*)qb, 8192, 8192, 8192, 4096);
  eagle3_gemm2<true, false><<<dim3(8, 32), blk, 0, stream>>>(
      (const void*)hs, wkbf, (void*)kbuf, 8192, 8192, 8192, 1024);
  eagle3_gemm2<true, false><<<dim3(8, 32), blk, 0, stream>>>(
      (const void*)hs, wvbf, (void*)vbuf, 8192, 8192, 8192, 1024);

  // 3) RoPE + V transpose
  eagle3_rope<<<dim3(32768), blk, 0, stream>>>(qb, cosT, sinT, 32, 4096, 8388608);
  eagle3_rope<<<dim3(8192), blk, 0, stream>>>(kbuf, cosT, sinT, 8, 1024, 2097152);
  eagle3_vtrans<<<dim3(32, 16), blk, 0, stream>>>(vbuf, vt);

  // 4) causal GQA flash attention -> ctx
  eagle3_flash2<<<dim3(32, 32, 2), blk, 0, stream>>>(qb, kbuf, vt, ctx);

  // 5) output projection: out = ctx * Wo^T (f32 out)
  eagle3_cvt<<<dim3(2048), blk, 0, stream>>>(Wo, wobf, 2097152);
  eagle3_gemm2<false, true><<<dim3(32, 32), blk, 0, stream>>>(
      (const void*)ctx, wobf, d_out, 4096, 4096, 4096, 4096);
}

// Round 4
// 2374.140 us; speedup vs baseline: 1.0866x; 1.0008x over previous
//
#include <hip/hip_runtime.h>
#include <stdint.h>

// ---------- common types / helpers ----------
typedef __attribute__((ext_vector_type(8))) short bf8;   // 8 x bf16 (4 VGPRs)
typedef __attribute__((ext_vector_type(4))) float f4;    // MFMA accumulator

__device__ __forceinline__ float bf2f(uint16_t u) {
  union { unsigned i; float f; } v; v.i = ((unsigned)u) << 16; return v.f;
}
__device__ __forceinline__ uint16_t f2bf(float f) {
  union { float f; unsigned i; } v; v.f = f;
  unsigned r = v.i + 0x7fffu + ((v.i >> 16) & 1u);   // RTNE
  return (uint16_t)(r >> 16);
}
__device__ __forceinline__ bf8 cvt8(float4 a, float4 b) {
  bf8 r;
  r[0]=(short)f2bf(a.x); r[1]=(short)f2bf(a.y); r[2]=(short)f2bf(a.z); r[3]=(short)f2bf(a.w);
  r[4]=(short)f2bf(b.x); r[5]=(short)f2bf(b.y); r[6]=(short)f2bf(b.z); r[7]=(short)f2bf(b.w);
  return r;
}

// async global->LDS, 16B per lane, wave-uniform LDS base + lane*16
__device__ __forceinline__ void gload_lds16(const void* g, void* l) {
  __builtin_amdgcn_global_load_lds(
      (const __attribute__((address_space(1))) uint32_t*)(uintptr_t)g,
      (__attribute__((address_space(3))) uint32_t*)(uint32_t)(uintptr_t)l,
      16, 0, 0);
}

// ---------- f32 -> bf16 bulk convert ----------
__global__ __launch_bounds__(256)
void eagle3_cvt(const float* __restrict__ src, uint16_t* __restrict__ dst, int n8)
{
  int i = blockIdx.x * 256 + threadIdx.x;
  const int stride = gridDim.x * 256;
  for (; i < n8; i += stride) {
    const float4 a = ((const float4*)src)[i * 2];
    const float4 b = ((const float4*)src)[i * 2 + 1];
    ((bf8*)dst)[i] = cvt8(a, b);
  }
}

// ---------- GEMM: C[M,N] = A[M,K] * B[N,K]^T ----------
// 128x128 tile, BK=32, 4 waves (2x2 of 64x64), mfma_f32_16x16x32_bf16.
// B (bf16) staged via global_load_lds w/ XOR chunk swizzle (c ^= (row>>1)&3),
// swizzle applied to the per-lane GLOBAL source addr, LDS stays linear; the
// fragment read applies the same XOR -> cancels (both-sides-or-neither rule).
// A: f32 reg-cvt staged into padded LDS (AF32) or bf16 via global_load_lds.
template<bool AF32, bool OF32>
__global__ __launch_bounds__(256)
void eagle3_gemm2(const void* __restrict__ Ap, const uint16_t* __restrict__ Bp,
                  void* __restrict__ Cp, int K, int lda, int ldb, int ldc)
{
  constexpr int ALD = AF32 ? 40 : 32;
  __shared__ __align__(16) uint16_t As[128 * ALD];
  __shared__ __align__(16) uint16_t Bs[128 * 32];

  // XCD-bijective block swizzle (nwg % 8 == 0 for all our grids)
  const int nwg = gridDim.x * gridDim.y;
  const int bid = blockIdx.y * gridDim.x + blockIdx.x;
  const int qq = nwg >> 3;
  const int sw = (bid & 7) * qq + (bid >> 3);
  const int bx = sw % gridDim.x, by = sw / gridDim.x;
  const int m0 = by * 128, n0 = bx * 128;

  const int tid = threadIdx.x, lane = tid & 63, w = tid >> 6;
  const int tl = lane & 15, g = lane >> 4;
  const int wr = (w >> 1) * 64, wc = (w & 1) * 64;

  f4 acc[4][4] = {};

  for (int k0 = 0; k0 < K; k0 += 32) {
    bf8 a0, a1;
    const int sr = tid >> 1, sc2 = (tid & 1) * 16;
    if constexpr (AF32) {
      const float* sa = (const float*)Ap + (size_t)(m0 + sr) * lda + k0 + sc2;
      a0 = cvt8(*(const float4*)(sa),     *(const float4*)(sa + 4));
      a1 = cvt8(*(const float4*)(sa + 8), *(const float4*)(sa + 12));
    }
    __syncthreads();                        // prev iteration's frag reads done
    if constexpr (AF32) {
      *(bf8*)&As[sr * 40 + sc2]     = a0;
      *(bf8*)&As[sr * 40 + sc2 + 8] = a1;
    } else {
      #pragma unroll
      for (int i = 0; i < 2; ++i) {
        const int o = (w * 2 + i) * 1024 + lane * 16;   // byte offset in 8KB tile
        const int r = o >> 6;
        const int u = (((o >> 4) & 3) ^ ((r >> 1) & 3)) * 8;
        gload_lds16((const uint16_t*)Ap + (size_t)(m0 + r) * lda + k0 + u,
                    &As[(w * 2 + i) * 512]);
      }
    }
    #pragma unroll
    for (int i = 0; i < 2; ++i) {
      const int o = (w * 2 + i) * 1024 + lane * 16;
      const int r = o >> 6;
      const int u = (((o >> 4) & 3) ^ ((r >> 1) & 3)) * 8;
      gload_lds16(Bp + (size_t)(n0 + r) * ldb + k0 + u, &Bs[(w * 2 + i) * 512]);
    }
    __syncthreads();                        // drains vmcnt + lgkm -> tiles visible

    bf8 af[4], bf_[4];
    #pragma unroll
    for (int i = 0; i < 4; ++i) {
      const int ar = wr + i * 16 + tl;
      const int br = wc + i * 16 + tl;
      if constexpr (AF32) af[i] = *(const bf8*)&As[ar * 40 + g * 8];
      else                af[i] = *(const bf8*)&As[ar * 32 + ((g ^ ((ar >> 1) & 3)) * 8)];
      bf_[i] = *(const bf8*)&Bs[br * 32 + ((g ^ ((br >> 1) & 3)) * 8)];
    }
    #pragma unroll
    for (int mi = 0; mi < 4; ++mi)
      #pragma unroll
      for (int ni = 0; ni < 4; ++ni)
        acc[mi][ni] = __builtin_amdgcn_mfma_f32_16x16x32_bf16(af[mi], bf_[ni], acc[mi][ni], 0, 0, 0);
  }

  // epilogue: C/D layout col=lane&15, row=(lane>>4)*4+reg
  #pragma unroll
  for (int mi = 0; mi < 4; ++mi) {
    #pragma unroll
    for (int r = 0; r < 4; ++r) {
      const int row = m0 + wr + mi * 16 + g * 4 + r;
      #pragma unroll
      for (int ni = 0; ni < 4; ++ni) {
        const int col = n0 + wc + ni * 16 + tl;
        const float v = acc[mi][ni][r];
        if constexpr (OF32) ((float*)Cp)[(size_t)row * ldc + col] = v;
        else                ((uint16_t*)Cp)[(size_t)row * ldc + col] = f2bf(v);
      }
    }
  }
}

// ---------- RoPE (in-place on bf16, pairs (d, d+64)) ----------
__global__ __launch_bounds__(256)
void eagle3_rope(uint16_t* __restrict__ x, const float* __restrict__ cs,
                 const float* __restrict__ sn, int nh, int rowlen, int total)
{
  int id = blockIdx.x * 256 + threadIdx.x;
  if (id >= total) return;
  int d = id & 63;
  int t = id >> 6;
  int head = t & (nh - 1);
  int row = t / nh;
  int s = row & 2047;
  size_t base = (size_t)row * rowlen + head * 128;
  float c = cs[s * 128 + d], si = sn[s * 128 + d];
  float x1 = bf2f(x[base + d]), x2 = bf2f(x[base + d + 64]);
  x[base + d]      = f2bf(x1 * c - x2 * si);
  x[base + d + 64] = f2bf(x2 * c + x1 * si);
}

// ---------- V transpose: [b,t,h,d] -> [b,h,d,t] ----------
__global__ __launch_bounds__(256)
void eagle3_vtrans(const uint16_t* __restrict__ V, uint16_t* __restrict__ Vt)
{
  __shared__ uint16_t T[64 * 136];   // [t=64][d=128 + pad 8]
  const int tid = threadIdx.x;
  const int t0 = blockIdx.x * 64;
  const int bh = blockIdx.y;         // b*8 + h
  const int b = bh >> 3, h = bh & 7;
  {
    const int r = tid >> 2, c0 = (tid & 3) * 32;
    const uint16_t* src = V + (size_t)(b * 2048 + t0 + r) * 1024 + h * 128 + c0;
    #pragma unroll
    for (int j = 0; j < 4; ++j)
      *(bf8*)&T[r * 136 + c0 + j * 8] = *(const bf8*)(src + j * 8);
  }
  __syncthreads();
  {
    const int d = tid >> 1, tc = (tid & 1) * 32;
    uint16_t* dst = Vt + ((size_t)bh * 128 + d) * 2048 + t0 + tc;
    #pragma unroll
    for (int cc = 0; cc < 4; ++cc) {
      bf8 v;
      #pragma unroll
      for (int j = 0; j < 8; ++j) v[j] = T[(tc + cc * 8 + j) * 136 + d];
      *(bf8*)&dst[cc * 8] = v;
    }
  }
}

// ---------- causal GQA flash attention v3 (register-pipelined K/V) ----------
// grid (S/64, NQ, B); 4 waves, each wave owns 16 Q rows; KV tile = 32.
// K/V fragments live in registers; each tile's loads are issued one tile
// ahead (K re-issued right after QK^T consumes it, V right after PV), so
// global latency is hidden under softmax + MFMA work. Longest-first qt order.
__global__ __launch_bounds__(256, 2)
void eagle3_flash3(const uint16_t* __restrict__ Q, const uint16_t* __restrict__ Kt,
                   const uint16_t* __restrict__ Vt, uint16_t* __restrict__ O)
{
  __shared__ __align__(16) uint16_t Pl[4 * 16 * 40];

  const int tid = threadIdx.x, lane = tid & 63, w = tid >> 6;
  const int tl = lane & 15, g = lane >> 4;
  const int qt = (int)gridDim.x - 1 - (int)blockIdx.x;   // longest-first
  const int hq = blockIdx.y, b = blockIdx.z;
  const int hkv = hq >> 2;
  const int qrow0 = qt * 64 + w * 16;

  // Q fragments (A-operand): row = tl, k = kb*32 + g*8
  bf8 qf[4];
  {
    const uint16_t* qp = Q + ((size_t)(b * 2048 + qrow0 + tl)) * 4096 + hq * 128 + g * 8;
    #pragma unroll
    for (int kb = 0; kb < 4; ++kb) qf[kb] = *(const bf8*)(qp + kb * 32);
  }

  const uint16_t* Kbase = Kt + (size_t)b * 2048 * 1024 + hkv * 128;
  const uint16_t* Vbase = Vt + ((size_t)(b * 8 + hkv) * 128) * 2048;

  f4 acc[8] = {};
  float rm[4] = {-3e38f, -3e38f, -3e38f, -3e38f};
  float rl[4] = {0.f, 0.f, 0.f, 0.f};

  const float scale = 0.08838834764831845f;   // 1/sqrt(128)
  const int ntw = (qrow0 + 47) >> 5;          // per-wave causal bound

  // preload K/V tile 0 into registers
  bf8 kf[8], vf[8];
  #pragma unroll
  for (int kb = 0; kb < 4; ++kb) {
    kf[kb]     = *(const bf8*)(Kbase + (size_t)(tl) * 1024 + kb * 32 + g * 8);
    kf[4 + kb] = *(const bf8*)(Kbase + (size_t)(16 + tl) * 1024 + kb * 32 + g * 8);
  }
  #pragma unroll
  for (int df = 0; df < 8; ++df)
    vf[df] = *(const bf8*)(Vbase + (size_t)(df * 16 + tl) * 2048 + g * 8);

  for (int tb = 0; tb < ntw; ++tb) {
    const int t0 = tb * 32;
    const int t1 = min(t0 + 32, 2016);   // prefetch tile (clamped: stays in ws)

    // -- QK^T: S(16x32) = Q(16x128) x K^T (kf already resident) --
    f4 s0 = {}, s1 = {};
    __builtin_amdgcn_s_setprio(1);
    #pragma unroll
    for (int kb = 0; kb < 4; ++kb) {
      s0 = __builtin_amdgcn_mfma_f32_16x16x32_bf16(qf[kb], kf[kb],     s0, 0, 0, 0);
      s1 = __builtin_amdgcn_mfma_f32_16x16x32_bf16(qf[kb], kf[4 + kb], s1, 0, 0, 0);
    }
    __builtin_amdgcn_s_setprio(0);

    // -- re-issue kf <- K tile tb+1 (in flight across softmax + PV) --
    #pragma unroll
    for (int kb = 0; kb < 4; ++kb) {
      kf[kb]     = *(const bf8*)(Kbase + (size_t)(t1 + tl) * 1024 + kb * 32 + g * 8);
      kf[4 + kb] = *(const bf8*)(Kbase + (size_t)(t1 + 16 + tl) * 1024 + kb * 32 + g * 8);
    }

    // -- online softmax (rows in 16-lane groups; cols = tl / 16+tl) --
    float p0[4], p1[4];
    #pragma unroll
    for (int r = 0; r < 4; ++r) {
      const int qg = qrow0 + g * 4 + r;
      float v0 = s0[r] * scale, v1 = s1[r] * scale;
      if (t0 + tl > qg)      v0 = -1e30f;
      if (t0 + 16 + tl > qg) v1 = -1e30f;
      float mx = fmaxf(v0, v1);
      mx = fmaxf(mx, __shfl_xor(mx, 1));
      mx = fmaxf(mx, __shfl_xor(mx, 2));
      mx = fmaxf(mx, __shfl_xor(mx, 4));
      mx = fmaxf(mx, __shfl_xor(mx, 8));
      if (mx > rm[r]) {                       // rescale only when max grows
        const float corr = __expf(rm[r] - mx);
        rl[r] *= corr;
        #pragma unroll
        for (int df = 0; df < 8; ++df) acc[df][r] *= corr;
        rm[r] = mx;
      }
      const float e0 = __expf(v0 - rm[r]), e1 = __expf(v1 - rm[r]);
      float sum = e0 + e1;
      sum += __shfl_xor(sum, 1);
      sum += __shfl_xor(sum, 2);
      sum += __shfl_xor(sum, 4);
      sum += __shfl_xor(sum, 8);
      rl[r] += sum;
      p0[r] = e0; p1[r] = e1;
    }

    // -- P -> LDS (per-wave region), re-read as A-fragment --
    uint16_t* Pw = &Pl[w * 16 * 40];
    #pragma unroll
    for (int r = 0; r < 4; ++r) {
      Pw[(g * 4 + r) * 40 + tl]      = f2bf(p0[r]);
      Pw[(g * 4 + r) * 40 + 16 + tl] = f2bf(p1[r]);
    }
    bf8 pf = *(const bf8*)&Pw[tl * 40 + g * 8];   // same-wave RAW

    // -- PV: acc(16x128) += P(16x32) x V(32x128) (vf resident) --
    __builtin_amdgcn_s_setprio(1);
    #pragma unroll
    for (int df = 0; df < 8; ++df)
      acc[df] = __builtin_amdgcn_mfma_f32_16x16x32_bf16(pf, vf[df], acc[df], 0, 0, 0);
    __builtin_amdgcn_s_setprio(0);

    // -- re-issue vf <- V tile tb+1 (in flight across next QK + softmax) --
    #pragma unroll
    for (int df = 0; df < 8; ++df)
      vf[df] = *(const bf8*)(Vbase + (size_t)(df * 16 + tl) * 2048 + t1 + g * 8);
  }

  // -- normalize + store ctx[b, q, hq*128 + d] --
  #pragma unroll
  for (int r = 0; r < 4; ++r) {
    const float inv = 1.0f / rl[r];
    const size_t ob = ((size_t)(b * 2048 + qrow0 + g * 4 + r)) * 4096 + hq * 128 + tl;
    #pragma unroll
    for (int df = 0; df < 8; ++df)
      O[ob + df * 16] = f2bf(acc[df][r] * inv);
  }
}

// ---------- launch ----------
extern "C" void kernel_launch(void* const* d_in, const int* in_sizes, int n_in,
                              void* d_out, int out_size, void* d_ws, size_t ws_size,
                              hipStream_t stream) {
  const float* hs   = (const float*)d_in[0];
  const float* cosT = (const float*)d_in[2];
  const float* sinT = (const float*)d_in[3];
  const float* Wq   = (const float*)d_in[4];
  const float* Wk   = (const float*)d_in[5];
  const float* Wv   = (const float*)d_in[6];
  const float* Wo   = (const float*)d_in[7];

  // ---- workspace liveness plan (peak 83,886,080 B, proven in rounds 0-3) ----
  // [ 0M,32M) qb    [4096,4096] bf16   live: Q gemm -> flash
  // [32M,40M) kbuf  [4096,1024] bf16   live: K gemm -> flash
  // [40M,48M) vbuf  [4096,1024] bf16   live: V gemm -> vtrans
  // [48M,64M) wkbf  [1024,8192] bf16   live: cvt -> K gemm      (16 MB)
  // [64M,80M) wvbf  [1024,8192] bf16   live: cvt -> V gemm      (16 MB)
  // [72M,80M) vt    [16,128,2048] bf16 live: vtrans -> flash  (over wvbf tail)
  // [40M,72M) ctx   [4096,4096] bf16   live: flash -> Wo gemm (over dead bufs)
  // wqbf = d_out (64 MB exact)  live: cvt -> Q gemm (dead before final write)
  // wobf = qb                   live: cvt -> Wo gemm (after flash read of qb)
  char* ws = (char*)d_ws;
  uint16_t* qb   = (uint16_t*)(ws);
  uint16_t* kbuf = (uint16_t*)(ws + 33554432);
  uint16_t* vbuf = (uint16_t*)(ws + 41943040);
  uint16_t* wkbf = (uint16_t*)(ws + 50331648);
  uint16_t* wvbf = (uint16_t*)(ws + 67108864);
  uint16_t* vt   = (uint16_t*)(ws + 75497472);
  uint16_t* ctx  = (uint16_t*)(ws + 41943040);
  uint16_t* wqbf = (uint16_t*)d_out;
  uint16_t* wobf = qb;

  const dim3 blk(256);

  // 1) weight conversions
  eagle3_cvt<<<dim3(2048), blk, 0, stream>>>(Wq, wqbf, 4194304);
  eagle3_cvt<<<dim3(2048), blk, 0, stream>>>(Wk, wkbf, 1048576);
  eagle3_cvt<<<dim3(2048), blk, 0, stream>>>(Wv, wvbf, 1048576);

  // 2) QKV projections (A = hs f32 in-kernel cvt, B = bf16 via global_load_lds)
  eagle3_gemm2<true, false><<<dim3(32, 32), blk, 0, stream>>>(
      (const void*)hs, wqbf, (void*)qb, 8192, 8192, 8192, 4096);
  eagle3_gemm2<true, false><<<dim3(8, 32), blk, 0, stream>>>(
      (const void*)hs, wkbf, (void*)kbuf, 8192, 8192, 8192, 1024);
  eagle3_gemm2<true, false><<<dim3(8, 32), blk, 0, stream>>>(
      (const void*)hs, wvbf, (void*)vbuf, 8192, 8192, 8192, 1024);

  // 3) RoPE + V transpose
  eagle3_rope<<<dim3(32768), blk, 0, stream>>>(qb, cosT, sinT, 32, 4096, 8388608);
  eagle3_rope<<<dim3(8192), blk, 0, stream>>>(kbuf, cosT, sinT, 8, 1024, 2097152);
  eagle3_vtrans<<<dim3(32, 16), blk, 0, stream>>>(vbuf, vt);

  // 4) causal GQA flash attention -> ctx
  eagle3_flash3<<<dim3(32, 32, 2), blk, 0, stream>>>(qb, kbuf, vt, ctx);

  // 5) output projection: out = ctx * Wo^T (f32 out)
  eagle3_cvt<<<dim3(2048), blk, 0, stream>>>(Wo, wobf, 2097152);
  eagle3_gemm2<false, true><<<dim3(32, 32), blk, 0, stream>>>(
      (const void*)ctx, wobf, d_out, 4096, 4096, 4096, 4096);
}

// Round 5
// 1700.168 us; speedup vs baseline: 1.5173x; 1.3964x over previous
//
#include <hip/hip_runtime.h>
#include <stdint.h>

// ---------- common types / helpers ----------
typedef __attribute__((ext_vector_type(8))) short bf8;   // 8 x bf16 (4 VGPRs)
typedef __attribute__((ext_vector_type(4))) float f4;    // MFMA accumulator

__device__ __forceinline__ float bf2f(uint16_t u) {
  union { unsigned i; float f; } v; v.i = ((unsigned)u) << 16; return v.f;
}
__device__ __forceinline__ uint16_t f2bf(float f) {
  union { float f; unsigned i; } v; v.f = f;
  unsigned r = v.i + 0x7fffu + ((v.i >> 16) & 1u);   // RTNE
  return (uint16_t)(r >> 16);
}
__device__ __forceinline__ bf8 cvt8(float4 a, float4 b) {
  bf8 r;
  r[0]=(short)f2bf(a.x); r[1]=(short)f2bf(a.y); r[2]=(short)f2bf(a.z); r[3]=(short)f2bf(a.w);
  r[4]=(short)f2bf(b.x); r[5]=(short)f2bf(b.y); r[6]=(short)f2bf(b.z); r[7]=(short)f2bf(b.w);
  return r;
}

// async global->LDS, 16B per lane, wave-uniform LDS base + lane*16
__device__ __forceinline__ void gload_lds16(const void* g, void* l) {
  __builtin_amdgcn_global_load_lds(
      (const __attribute__((address_space(1))) uint32_t*)(uintptr_t)g,
      (__attribute__((address_space(3))) uint32_t*)(uint32_t)(uintptr_t)l,
      16, 0, 0);
}

// ---------- f32 -> bf16 bulk convert ----------
__global__ __launch_bounds__(256)
void eagle3_cvt(const float* __restrict__ src, uint16_t* __restrict__ dst, int n8)
{
  int i = blockIdx.x * 256 + threadIdx.x;
  const int stride = gridDim.x * 256;
  for (; i < n8; i += stride) {
    const float4 a = ((const float4*)src)[i * 2];
    const float4 b = ((const float4*)src)[i * 2 + 1];
    ((bf8*)dst)[i] = cvt8(a, b);
  }
}

// ---------- GEMM: C[M,N] = A[M,K] * B[N,K]^T ----------
// 128x128 tile, BK=32, 4 waves (2x2 of 64x64), mfma_f32_16x16x32_bf16.
template<bool AF32, bool OF32>
__global__ __launch_bounds__(256)
void eagle3_gemm2(const void* __restrict__ Ap, const uint16_t* __restrict__ Bp,
                  void* __restrict__ Cp, int K, int lda, int ldb, int ldc)
{
  constexpr int ALD = AF32 ? 40 : 32;
  __shared__ __align__(16) uint16_t As[128 * ALD];
  __shared__ __align__(16) uint16_t Bs[128 * 32];

  // XCD-bijective block swizzle (nwg % 8 == 0 for all our grids)
  const int nwg = gridDim.x * gridDim.y;
  const int bid = blockIdx.y * gridDim.x + blockIdx.x;
  const int qq = nwg >> 3;
  const int sw = (bid & 7) * qq + (bid >> 3);
  const int bx = sw % gridDim.x, by = sw / gridDim.x;
  const int m0 = by * 128, n0 = bx * 128;

  const int tid = threadIdx.x, lane = tid & 63, w = tid >> 6;
  const int tl = lane & 15, g = lane >> 4;
  const int wr = (w >> 1) * 64, wc = (w & 1) * 64;

  f4 acc[4][4] = {};

  for (int k0 = 0; k0 < K; k0 += 32) {
    bf8 a0, a1;
    const int sr = tid >> 1, sc2 = (tid & 1) * 16;
    if constexpr (AF32) {
      const float* sa = (const float*)Ap + (size_t)(m0 + sr) * lda + k0 + sc2;
      a0 = cvt8(*(const float4*)(sa),     *(const float4*)(sa + 4));
      a1 = cvt8(*(const float4*)(sa + 8), *(const float4*)(sa + 12));
    }
    __syncthreads();                        // prev iteration's frag reads done
    if constexpr (AF32) {
      *(bf8*)&As[sr * 40 + sc2]     = a0;
      *(bf8*)&As[sr * 40 + sc2 + 8] = a1;
    } else {
      #pragma unroll
      for (int i = 0; i < 2; ++i) {
        const int o = (w * 2 + i) * 1024 + lane * 16;   // byte offset in 8KB tile
        const int r = o >> 6;
        const int u = (((o >> 4) & 3) ^ ((r >> 1) & 3)) * 8;
        gload_lds16((const uint16_t*)Ap + (size_t)(m0 + r) * lda + k0 + u,
                    &As[(w * 2 + i) * 512]);
      }
    }
    #pragma unroll
    for (int i = 0; i < 2; ++i) {
      const int o = (w * 2 + i) * 1024 + lane * 16;
      const int r = o >> 6;
      const int u = (((o >> 4) & 3) ^ ((r >> 1) & 3)) * 8;
      gload_lds16(Bp + (size_t)(n0 + r) * ldb + k0 + u, &Bs[(w * 2 + i) * 512]);
    }
    __syncthreads();                        // drains vmcnt + lgkm -> tiles visible

    bf8 af[4], bf_[4];
    #pragma unroll
    for (int i = 0; i < 4; ++i) {
      const int ar = wr + i * 16 + tl;
      const int br = wc + i * 16 + tl;
      if constexpr (AF32) af[i] = *(const bf8*)&As[ar * 40 + g * 8];
      else                af[i] = *(const bf8*)&As[ar * 32 + ((g ^ ((ar >> 1) & 3)) * 8)];
      bf_[i] = *(const bf8*)&Bs[br * 32 + ((g ^ ((br >> 1) & 3)) * 8)];
    }
    #pragma unroll
    for (int mi = 0; mi < 4; ++mi)
      #pragma unroll
      for (int ni = 0; ni < 4; ++ni)
        acc[mi][ni] = __builtin_amdgcn_mfma_f32_16x16x32_bf16(af[mi], bf_[ni], acc[mi][ni], 0, 0, 0);
  }

  // epilogue: C/D layout col=lane&15, row=(lane>>4)*4+reg
  #pragma unroll
  for (int mi = 0; mi < 4; ++mi) {
    #pragma unroll
    for (int r = 0; r < 4; ++r) {
      const int row = m0 + wr + mi * 16 + g * 4 + r;
      #pragma unroll
      for (int ni = 0; ni < 4; ++ni) {
        const int col = n0 + wc + ni * 16 + tl;
        const float v = acc[mi][ni][r];
        if constexpr (OF32) ((float*)Cp)[(size_t)row * ldc + col] = v;
        else                ((uint16_t*)Cp)[(size_t)row * ldc + col] = f2bf(v);
      }
    }
  }
}

// ---------- RoPE (in-place on bf16, pairs (d, d+64)) ----------
__global__ __launch_bounds__(256)
void eagle3_rope(uint16_t* __restrict__ x, const float* __restrict__ cs,
                 const float* __restrict__ sn, int nh, int rowlen, int total)
{
  int id = blockIdx.x * 256 + threadIdx.x;
  if (id >= total) return;
  int d = id & 63;
  int t = id >> 6;
  int head = t & (nh - 1);
  int row = t / nh;
  int s = row & 2047;
  size_t base = (size_t)row * rowlen + head * 128;
  float c = cs[s * 128 + d], si = sn[s * 128 + d];
  float x1 = bf2f(x[base + d]), x2 = bf2f(x[base + d + 64]);
  x[base + d]      = f2bf(x1 * c - x2 * si);
  x[base + d + 64] = f2bf(x2 * c + x1 * si);
}

// ---------- V transpose: [b,t,h,d] -> [b,h,d,t] ----------
__global__ __launch_bounds__(256)
void eagle3_vtrans(const uint16_t* __restrict__ V, uint16_t* __restrict__ Vt)
{
  __shared__ uint16_t T[64 * 136];   // [t=64][d=128 + pad 8]
  const int tid = threadIdx.x;
  const int t0 = blockIdx.x * 64;
  const int bh = blockIdx.y;         // b*8 + h
  const int b = bh >> 3, h = bh & 7;
  {
    const int r = tid >> 2, c0 = (tid & 3) * 32;
    const uint16_t* src = V + (size_t)(b * 2048 + t0 + r) * 1024 + h * 128 + c0;
    #pragma unroll
    for (int j = 0; j < 4; ++j)
      *(bf8*)&T[r * 136 + c0 + j * 8] = *(const bf8*)(src + j * 8);
  }
  __syncthreads();
  {
    const int d = tid >> 1, tc = (tid & 1) * 32;
    uint16_t* dst = Vt + ((size_t)bh * 128 + d) * 2048 + t0 + tc;
    #pragma unroll
    for (int cc = 0; cc < 4; ++cc) {
      bf8 v;
      #pragma unroll
      for (int j = 0; j < 8; ++j) v[j] = T[(tc + cc * 8 + j) * 136 + d];
      *(bf8*)&dst[cc * 8] = v;
    }
  }
}

// ---------- causal GQA flash attention v4 (LDS double-buffer + DMA) ----------
// QBLK=64 (4 waves x 16 rows), KVBLK=64. K/V tiles staged via global_load_lds
// into double-buffered LDS; counted s_waitcnt vmcnt(8) keeps next tile's DMA
// in flight across compute (never drains to 0 in the loop). Raw s_barrier
// (no compiler vmcnt(0) drain). XOR chunk swizzle (c ^= row&7) applied on the
// GLOBAL source addr (LDS linear) and re-applied on ds_read -> conflict-free.
// XCD remap: each XCD owns 2 (b,hkv) groups -> K/V L2-resident (2MB/XCD).
__global__ __launch_bounds__(256, 2)
void eagle3_flash4(const uint16_t* __restrict__ Q, const uint16_t* __restrict__ Kt,
                   const uint16_t* __restrict__ Vt, uint16_t* __restrict__ O)
{
  __shared__ __align__(16) uint16_t Ks[2][64 * 128];
  __shared__ __align__(16) uint16_t Vs[2][128 * 64];
  __shared__ __align__(16) uint16_t Pl[4][16 * 72];

  const int tid = threadIdx.x, lane = tid & 63, w = tid >> 6;
  const int tl = lane & 15, g = lane >> 4;

  // XCD-aware remap: bid%8 ~ XCD (round-robin dispatch heuristic).
  // Each XCD gets 2 (b,hkv) groups; within a group: 4 hq x 32 qt, heavy first.
  const int bid = (int)blockIdx.x + ((int)blockIdx.y << 5) + ((int)blockIdx.z << 10);
  const int xcd = bid & 7, idx = bid >> 3;
  const int grp = xcd * 2 + (idx >> 7);          // b*8 + hkv
  const int j   = idx & 127;
  const int b = grp >> 3, hkv = grp & 7;
  const int hq = hkv * 4 + (j & 3);
  const int qt = 31 - (j >> 2);
  const int qrow0 = qt * 64 + w * 16;
  const int ntb = qt + 1;                        // block-uniform 64-wide KV tiles

  // Q fragments (A-operand): row = tl, k = kb*32 + g*8  (4 global loads/wave)
  bf8 qf[4];
  {
    const uint16_t* qp = Q + ((size_t)(b * 2048 + qrow0 + tl)) * 4096 + hq * 128 + g * 8;
    #pragma unroll
    for (int kb = 0; kb < 4; ++kb) qf[kb] = *(const bf8*)(qp + kb * 32);
  }

  const uint16_t* Kbase = Kt + (size_t)b * 2048 * 1024 + hkv * 128;   // [t][128]
  const uint16_t* Vtb   = Vt + ((size_t)(b * 8 + hkv) * 128) * 2048;  // [d][t]

  f4 acc[8] = {};
  float rm[4] = {-3e38f, -3e38f, -3e38f, -3e38f};
  float rl[4] = {0.f, 0.f, 0.f, 0.f};
  const float scale = 0.08838834764831845f;   // 1/sqrt(128)

  // ---- staging: 8 gload_lds16 per thread per tile (4 K-chunks + 4 V-chunks)
  // K tile: 64 rows x 16 chunks; source chunk pre-swizzled c^(row&7).
  // V tile: 128 d-rows x 8 chunks;  source chunk pre-swizzled c^(d&7).
  #define STAGE_TILE(buf, t0s)                                                   \
    {                                                                            \
      _Pragma("unroll")                                                          \
      for (int i = 0; i < 4; ++i) {                                              \
        const int f = i * 256 + tid;                                             \
        const int r = f >> 4, c = f & 15;                                        \
        gload_lds16(Kbase + (size_t)((t0s) + r) * 1024 + ((c ^ (r & 7)) * 8),    \
                    &Ks[buf][(i * 256 + w * 64) * 8]);                           \
      }                                                                          \
      _Pragma("unroll")                                                          \
      for (int i = 0; i < 4; ++i) {                                              \
        const int f = i * 256 + tid;                                             \
        const int d = f >> 3, c = f & 7;                                         \
        gload_lds16(Vtb + (size_t)d * 2048 + (t0s) + ((c ^ (d & 7)) * 8),        \
                    &Vs[buf][(i * 256 + w * 64) * 8]);                           \
      }                                                                          \
    }

  STAGE_TILE(0, 0);                              // prologue: tile 0 in flight

  for (int tb = 0; tb < ntb; ++tb) {
    const int cur = tb & 1;
    const int t0 = tb * 64;

    if (tb + 1 < ntb) {
      STAGE_TILE(cur ^ 1, t0 + 64);              // issue next tile's DMA
      asm volatile("s_waitcnt vmcnt(8)" ::: "memory");   // tile tb landed
    } else {
      asm volatile("s_waitcnt vmcnt(0)" ::: "memory");   // drain (clean exit)
    }
    __builtin_amdgcn_sched_barrier(0);
    __builtin_amdgcn_s_barrier();                // all waves' quarters visible

    // -- QK^T: S(16x64) = Q(16x128) x K^T, four 16-col fragments --
    f4 s[4] = {};
    __builtin_amdgcn_s_setprio(1);
    #pragma unroll
    for (int cf = 0; cf < 4; ++cf) {
      #pragma unroll
      for (int kb = 0; kb < 4; ++kb) {
        const bf8 kf = *(const bf8*)&Ks[cur][(cf * 16 + tl) * 128 +
                                            (((kb * 4 + g) ^ (tl & 7)) * 8)];
        s[cf] = __builtin_amdgcn_mfma_f32_16x16x32_bf16(qf[kb], kf, s[cf], 0, 0, 0);
      }
    }
    __builtin_amdgcn_s_setprio(0);

    // -- online softmax (rows in 16-lane groups; 4 col-fragments) --
    float p[4][4];
    #pragma unroll
    for (int r = 0; r < 4; ++r) {
      const int qg = qrow0 + g * 4 + r;
      float v[4];
      #pragma unroll
      for (int cf = 0; cf < 4; ++cf) {
        v[cf] = s[cf][r] * scale;
        if (t0 + cf * 16 + tl > qg) v[cf] = -1e30f;
      }
      float mx = fmaxf(fmaxf(v[0], v[1]), fmaxf(v[2], v[3]));
      mx = fmaxf(mx, __shfl_xor(mx, 1));
      mx = fmaxf(mx, __shfl_xor(mx, 2));
      mx = fmaxf(mx, __shfl_xor(mx, 4));
      mx = fmaxf(mx, __shfl_xor(mx, 8));
      if (mx > rm[r]) {                           // rescale only when max grows
        const float corr = __expf(rm[r] - mx);
        rl[r] *= corr;
        #pragma unroll
        for (int df = 0; df < 8; ++df) acc[df][r] *= corr;
        rm[r] = mx;
      }
      float sum = 0.f;
      #pragma unroll
      for (int cf = 0; cf < 4; ++cf) { p[r][cf] = __expf(v[cf] - rm[r]); sum += p[r][cf]; }
      sum += __shfl_xor(sum, 1);
      sum += __shfl_xor(sum, 2);
      sum += __shfl_xor(sum, 4);
      sum += __shfl_xor(sum, 8);
      rl[r] += sum;
    }

    // -- P -> LDS (per-wave region, stride 72), re-read as A-fragments --
    #pragma unroll
    for (int r = 0; r < 4; ++r)
      #pragma unroll
      for (int cf = 0; cf < 4; ++cf)
        Pl[w][(g * 4 + r) * 72 + cf * 16 + tl] = f2bf(p[r][cf]);
    const bf8 pf0 = *(const bf8*)&Pl[w][tl * 72 + g * 8];        // k = 0..31
    const bf8 pf1 = *(const bf8*)&Pl[w][tl * 72 + 32 + g * 8];   // k = 32..63

    // -- PV: acc(16x128) += P(16x64) x V(64x128) --
    __builtin_amdgcn_s_setprio(1);
    #pragma unroll
    for (int df = 0; df < 8; ++df) {
      const int vrow = (df * 16 + tl) * 64;
      const bf8 v0 = *(const bf8*)&Vs[cur][vrow + ((g ^ (tl & 7)) * 8)];
      const bf8 v1 = *(const bf8*)&Vs[cur][vrow + (((4 + g) ^ (tl & 7)) * 8)];
      acc[df] = __builtin_amdgcn_mfma_f32_16x16x32_bf16(pf0, v0, acc[df], 0, 0, 0);
      acc[df] = __builtin_amdgcn_mfma_f32_16x16x32_bf16(pf1, v1, acc[df], 0, 0, 0);
    }
    __builtin_amdgcn_s_setprio(0);

    __builtin_amdgcn_s_barrier();                // done reading buf before restage
  }
  #undef STAGE_TILE

  // -- normalize + store ctx[b, q, hq*128 + d] --
  #pragma unroll
  for (int r = 0; r < 4; ++r) {
    const float inv = 1.0f / rl[r];
    const size_t ob = ((size_t)(b * 2048 + qrow0 + g * 4 + r)) * 4096 + hq * 128 + tl;
    #pragma unroll
    for (int df = 0; df < 8; ++df)
      O[ob + df * 16] = f2bf(acc[df][r] * inv);
  }
}

// ---------- launch ----------
extern "C" void kernel_launch(void* const* d_in, const int* in_sizes, int n_in,
                              void* d_out, int out_size, void* d_ws, size_t ws_size,
                              hipStream_t stream) {
  const float* hs   = (const float*)d_in[0];
  const float* cosT = (const float*)d_in[2];
  const float* sinT = (const float*)d_in[3];
  const float* Wq   = (const float*)d_in[4];
  const float* Wk   = (const float*)d_in[5];
  const float* Wv   = (const float*)d_in[6];
  const float* Wo   = (const float*)d_in[7];

  // ---- workspace liveness plan (peak 83,886,080 B, proven rounds 0-4) ----
  char* ws = (char*)d_ws;
  uint16_t* qb   = (uint16_t*)(ws);                 // [ 0M,32M)
  uint16_t* kbuf = (uint16_t*)(ws + 33554432);      // [32M,40M)
  uint16_t* vbuf = (uint16_t*)(ws + 41943040);      // [40M,48M)
  uint16_t* wkbf = (uint16_t*)(ws + 50331648);      // [48M,64M)
  uint16_t* wvbf = (uint16_t*)(ws + 67108864);      // [64M,80M)
  uint16_t* vt   = (uint16_t*)(ws + 75497472);      // [72M,80M) over wvbf tail
  uint16_t* ctx  = (uint16_t*)(ws + 41943040);      // [40M,72M) over dead bufs
  uint16_t* wqbf = (uint16_t*)d_out;                // 64 MB exact, dies pre-out
  uint16_t* wobf = qb;                              // after flash reads qb

  const dim3 blk(256);

  // 1) weight conversions
  eagle3_cvt<<<dim3(2048), blk, 0, stream>>>(Wq, wqbf, 4194304);
  eagle3_cvt<<<dim3(2048), blk, 0, stream>>>(Wk, wkbf, 1048576);
  eagle3_cvt<<<dim3(2048), blk, 0, stream>>>(Wv, wvbf, 1048576);

  // 2) QKV projections (A = hs f32 in-kernel cvt, B = bf16 via global_load_lds)
  eagle3_gemm2<true, false><<<dim3(32, 32), blk, 0, stream>>>(
      (const void*)hs, wqbf, (void*)qb, 8192, 8192, 8192, 4096);
  eagle3_gemm2<true, false><<<dim3(8, 32), blk, 0, stream>>>(
      (const void*)hs, wkbf, (void*)kbuf, 8192, 8192, 8192, 1024);
  eagle3_gemm2<true, false><<<dim3(8, 32), blk, 0, stream>>>(
      (const void*)hs, wvbf, (void*)vbuf, 8192, 8192, 8192, 1024);

  // 3) RoPE + V transpose
  eagle3_rope<<<dim3(32768), blk, 0, stream>>>(qb, cosT, sinT, 32, 4096, 8388608);
  eagle3_rope<<<dim3(8192), blk, 0, stream>>>(kbuf, cosT, sinT, 8, 1024, 2097152);
  eagle3_vtrans<<<dim3(32, 16), blk, 0, stream>>>(vbuf, vt);

  // 4) causal GQA flash attention -> ctx
  eagle3_flash4<<<dim3(32, 32, 2), blk, 0, stream>>>(qb, kbuf, vt, ctx);

  // 5) output projection: out = ctx * Wo^T (f32 out)
  eagle3_cvt<<<dim3(2048), blk, 0, stream>>>(Wo, wobf, 2097152);
  eagle3_gemm2<false, true><<<dim3(32, 32), blk, 0, stream>>>(
      (const void*)ctx, wobf, d_out, 4096, 4096, 4096, 4096);
}

// Round 6
// 1221.594 us; speedup vs baseline: 2.1117x; 1.3918x over previous
//
#include <hip/hip_runtime.h>
#include <stdint.h>

// ---------- common types / helpers ----------
typedef __attribute__((ext_vector_type(8))) short bf8;   // 8 x bf16 (4 VGPRs)
typedef __attribute__((ext_vector_type(4))) float f4;    // MFMA accumulator

__device__ __forceinline__ float bf2f(uint16_t u) {
  union { unsigned i; float f; } v; v.i = ((unsigned)u) << 16; return v.f;
}
__device__ __forceinline__ uint16_t f2bf(float f) {
  union { float f; unsigned i; } v; v.f = f;
  unsigned r = v.i + 0x7fffu + ((v.i >> 16) & 1u);   // RTNE
  return (uint16_t)(r >> 16);
}
__device__ __forceinline__ bf8 cvt8(float4 a, float4 b) {
  bf8 r;
  r[0]=(short)f2bf(a.x); r[1]=(short)f2bf(a.y); r[2]=(short)f2bf(a.z); r[3]=(short)f2bf(a.w);
  r[4]=(short)f2bf(b.x); r[5]=(short)f2bf(b.y); r[6]=(short)f2bf(b.z); r[7]=(short)f2bf(b.w);
  return r;
}

// async global->LDS, 16B per lane, wave-uniform LDS base + lane*16
__device__ __forceinline__ void gload_lds16(const void* g, void* l) {
  __builtin_amdgcn_global_load_lds(
      (const __attribute__((address_space(1))) uint32_t*)(uintptr_t)g,
      (__attribute__((address_space(3))) uint32_t*)(uint32_t)(uintptr_t)l,
      16, 0, 0);
}

// ---------- f32 -> bf16 bulk convert ----------
__global__ __launch_bounds__(256)
void eagle3_cvt(const float* __restrict__ src, uint16_t* __restrict__ dst, int n8)
{
  int i = blockIdx.x * 256 + threadIdx.x;
  const int stride = gridDim.x * 256;
  for (; i < n8; i += stride) {
    const float4 a = ((const float4*)src)[i * 2];
    const float4 b = ((const float4*)src)[i * 2 + 1];
    ((bf8*)dst)[i] = cvt8(a, b);
  }
}

// ---------- GEMM: C[M,N] = A[M,K] * B[N,K]^T (both bf16) ----------
// 128x128 tile, BK=32, 4 waves (2x2 of 64x64), mfma_f32_16x16x32_bf16.
// A and B staged via global_load_lds w/ XOR chunk swizzle (c ^= (row>>1)&3)
// applied to the per-lane GLOBAL source addr (LDS linear); the fragment read
// applies the same XOR -> cancels (both-sides-or-neither rule).
template<bool OF32>
__global__ __launch_bounds__(256)
void eagle3_gemm2(const uint16_t* __restrict__ Ap, const uint16_t* __restrict__ Bp,
                  void* __restrict__ Cp, int K, int lda, int ldb, int ldc)
{
  __shared__ __align__(16) uint16_t As[128 * 32];
  __shared__ __align__(16) uint16_t Bs[128 * 32];

  // XCD-bijective block swizzle (nwg % 8 == 0 for all our grids)
  const int nwg = gridDim.x * gridDim.y;
  const int bid = blockIdx.y * gridDim.x + blockIdx.x;
  const int qq = nwg >> 3;
  const int sw = (bid & 7) * qq + (bid >> 3);
  const int bx = sw % gridDim.x, by = sw / gridDim.x;
  const int m0 = by * 128, n0 = bx * 128;

  const int tid = threadIdx.x, lane = tid & 63, w = tid >> 6;
  const int tl = lane & 15, g = lane >> 4;
  const int wr = (w >> 1) * 64, wc = (w & 1) * 64;

  f4 acc[4][4] = {};

  for (int k0 = 0; k0 < K; k0 += 32) {
    __syncthreads();                        // prev iteration's frag reads done
    #pragma unroll
    for (int i = 0; i < 2; ++i) {
      const int o = (w * 2 + i) * 1024 + lane * 16;   // byte offset in 8KB tile
      const int r = o >> 6;
      const int u = (((o >> 4) & 3) ^ ((r >> 1) & 3)) * 8;
      gload_lds16(Ap + (size_t)(m0 + r) * lda + k0 + u, &As[(w * 2 + i) * 512]);
    }
    #pragma unroll
    for (int i = 0; i < 2; ++i) {
      const int o = (w * 2 + i) * 1024 + lane * 16;
      const int r = o >> 6;
      const int u = (((o >> 4) & 3) ^ ((r >> 1) & 3)) * 8;
      gload_lds16(Bp + (size_t)(n0 + r) * ldb + k0 + u, &Bs[(w * 2 + i) * 512]);
    }
    __syncthreads();                        // drains vmcnt + lgkm -> tiles visible

    bf8 af[4], bf_[4];
    #pragma unroll
    for (int i = 0; i < 4; ++i) {
      const int ar = wr + i * 16 + tl;
      const int br = wc + i * 16 + tl;
      af[i]  = *(const bf8*)&As[ar * 32 + ((g ^ ((ar >> 1) & 3)) * 8)];
      bf_[i] = *(const bf8*)&Bs[br * 32 + ((g ^ ((br >> 1) & 3)) * 8)];
    }
    #pragma unroll
    for (int mi = 0; mi < 4; ++mi)
      #pragma unroll
      for (int ni = 0; ni < 4; ++ni)
        acc[mi][ni] = __builtin_amdgcn_mfma_f32_16x16x32_bf16(af[mi], bf_[ni], acc[mi][ni], 0, 0, 0);
  }

  // epilogue: C/D layout col=lane&15, row=(lane>>4)*4+reg
  #pragma unroll
  for (int mi = 0; mi < 4; ++mi) {
    #pragma unroll
    for (int r = 0; r < 4; ++r) {
      const int row = m0 + wr + mi * 16 + g * 4 + r;
      #pragma unroll
      for (int ni = 0; ni < 4; ++ni) {
        const int col = n0 + wc + ni * 16 + tl;
        const float v = acc[mi][ni][r];
        if constexpr (OF32) ((float*)Cp)[(size_t)row * ldc + col] = v;
        else                ((uint16_t*)Cp)[(size_t)row * ldc + col] = f2bf(v);
      }
    }
  }
}

// ---------- RoPE (in-place on bf16, pairs (d, d+64)) ----------
__global__ __launch_bounds__(256)
void eagle3_rope(uint16_t* __restrict__ x, const float* __restrict__ cs,
                 const float* __restrict__ sn, int nh, int rowlen, int total)
{
  int id = blockIdx.x * 256 + threadIdx.x;
  if (id >= total) return;
  int d = id & 63;
  int t = id >> 6;
  int head = t & (nh - 1);
  int row = t / nh;
  int s = row & 2047;
  size_t base = (size_t)row * rowlen + head * 128;
  float c = cs[s * 128 + d], si = sn[s * 128 + d];
  float x1 = bf2f(x[base + d]), x2 = bf2f(x[base + d + 64]);
  x[base + d]      = f2bf(x1 * c - x2 * si);
  x[base + d + 64] = f2bf(x2 * c + x1 * si);
}

// ---------- V transpose: [b,t,h,d] -> [b,h,d,t] ----------
__global__ __launch_bounds__(256)
void eagle3_vtrans(const uint16_t* __restrict__ V, uint16_t* __restrict__ Vt)
{
  __shared__ uint16_t T[64 * 136];   // [t=64][d=128 + pad 8]
  const int tid = threadIdx.x;
  const int t0 = blockIdx.x * 64;
  const int bh = blockIdx.y;         // b*8 + h
  const int b = bh >> 3, h = bh & 7;
  {
    const int r = tid >> 2, c0 = (tid & 3) * 32;
    const uint16_t* src = V + (size_t)(b * 2048 + t0 + r) * 1024 + h * 128 + c0;
    #pragma unroll
    for (int j = 0; j < 4; ++j)
      *(bf8*)&T[r * 136 + c0 + j * 8] = *(const bf8*)(src + j * 8);
  }
  __syncthreads();
  {
    const int d = tid >> 1, tc = (tid & 1) * 32;
    uint16_t* dst = Vt + ((size_t)bh * 128 + d) * 2048 + t0 + tc;
    #pragma unroll
    for (int cc = 0; cc < 4; ++cc) {
      bf8 v;
      #pragma unroll
      for (int j = 0; j < 8; ++j) v[j] = T[(tc + cc * 8 + j) * 136 + d];
      *(bf8*)&dst[cc * 8] = v;
    }
  }
}

// ---------- causal GQA flash attention v4 (LDS double-buffer + DMA) ----------
// QBLK=64 (4 waves x 16 rows), KVBLK=64. K/V tiles staged via global_load_lds
// into double-buffered LDS; counted s_waitcnt vmcnt(8) keeps next tile's DMA
// in flight across compute. Raw s_barrier. XOR chunk swizzle both-sides.
// XCD remap: each XCD owns 2 (b,hkv) groups -> K/V L2-resident (2MB/XCD).
__global__ __launch_bounds__(256, 2)
void eagle3_flash4(const uint16_t* __restrict__ Q, const uint16_t* __restrict__ Kt,
                   const uint16_t* __restrict__ Vt, uint16_t* __restrict__ O)
{
  __shared__ __align__(16) uint16_t Ks[2][64 * 128];
  __shared__ __align__(16) uint16_t Vs[2][128 * 64];
  __shared__ __align__(16) uint16_t Pl[4][16 * 72];

  const int tid = threadIdx.x, lane = tid & 63, w = tid >> 6;
  const int tl = lane & 15, g = lane >> 4;

  const int bid = (int)blockIdx.x + ((int)blockIdx.y << 5) + ((int)blockIdx.z << 10);
  const int xcd = bid & 7, idx = bid >> 3;
  const int grp = xcd * 2 + (idx >> 7);          // b*8 + hkv
  const int j   = idx & 127;
  const int b = grp >> 3, hkv = grp & 7;
  const int hq = hkv * 4 + (j & 3);
  const int qt = 31 - (j >> 2);
  const int qrow0 = qt * 64 + w * 16;
  const int ntb = qt + 1;                        // block-uniform 64-wide KV tiles

  // Q fragments (A-operand): row = tl, k = kb*32 + g*8
  bf8 qf[4];
  {
    const uint16_t* qp = Q + ((size_t)(b * 2048 + qrow0 + tl)) * 4096 + hq * 128 + g * 8;
    #pragma unroll
    for (int kb = 0; kb < 4; ++kb) qf[kb] = *(const bf8*)(qp + kb * 32);
  }

  const uint16_t* Kbase = Kt + (size_t)b * 2048 * 1024 + hkv * 128;   // [t][128]
  const uint16_t* Vtb   = Vt + ((size_t)(b * 8 + hkv) * 128) * 2048;  // [d][t]

  f4 acc[8] = {};
  float rm[4] = {-3e38f, -3e38f, -3e38f, -3e38f};
  float rl[4] = {0.f, 0.f, 0.f, 0.f};
  const float scale = 0.08838834764831845f;   // 1/sqrt(128)

  #define STAGE_TILE(buf, t0s)                                                   \
    {                                                                            \
      _Pragma("unroll")                                                          \
      for (int i = 0; i < 4; ++i) {                                              \
        const int f = i * 256 + tid;                                             \
        const int r = f >> 4, c = f & 15;                                        \
        gload_lds16(Kbase + (size_t)((t0s) + r) * 1024 + ((c ^ (r & 7)) * 8),    \
                    &Ks[buf][(i * 256 + w * 64) * 8]);                           \
      }                                                                          \
      _Pragma("unroll")                                                          \
      for (int i = 0; i < 4; ++i) {                                              \
        const int f = i * 256 + tid;                                             \
        const int d = f >> 3, c = f & 7;                                         \
        gload_lds16(Vtb + (size_t)d * 2048 + (t0s) + ((c ^ (d & 7)) * 8),        \
                    &Vs[buf][(i * 256 + w * 64) * 8]);                           \
      }                                                                          \
    }

  STAGE_TILE(0, 0);                              // prologue: tile 0 in flight

  for (int tb = 0; tb < ntb; ++tb) {
    const int cur = tb & 1;
    const int t0 = tb * 64;

    if (tb + 1 < ntb) {
      STAGE_TILE(cur ^ 1, t0 + 64);              // issue next tile's DMA
      asm volatile("s_waitcnt vmcnt(8)" ::: "memory");   // tile tb landed
    } else {
      asm volatile("s_waitcnt vmcnt(0)" ::: "memory");   // drain (clean exit)
    }
    __builtin_amdgcn_sched_barrier(0);
    __builtin_amdgcn_s_barrier();                // all waves' quarters visible

    // -- QK^T: S(16x64) = Q(16x128) x K^T, four 16-col fragments --
    f4 s[4] = {};
    __builtin_amdgcn_s_setprio(1);
    #pragma unroll
    for (int cf = 0; cf < 4; ++cf) {
      #pragma unroll
      for (int kb = 0; kb < 4; ++kb) {
        const bf8 kf = *(const bf8*)&Ks[cur][(cf * 16 + tl) * 128 +
                                            (((kb * 4 + g) ^ (tl & 7)) * 8)];
        s[cf] = __builtin_amdgcn_mfma_f32_16x16x32_bf16(qf[kb], kf, s[cf], 0, 0, 0);
      }
    }
    __builtin_amdgcn_s_setprio(0);

    // -- online softmax (rows in 16-lane groups; 4 col-fragments) --
    float p[4][4];
    #pragma unroll
    for (int r = 0; r < 4; ++r) {
      const int qg = qrow0 + g * 4 + r;
      float v[4];
      #pragma unroll
      for (int cf = 0; cf < 4; ++cf) {
        v[cf] = s[cf][r] * scale;
        if (t0 + cf * 16 + tl > qg) v[cf] = -1e30f;
      }
      float mx = fmaxf(fmaxf(v[0], v[1]), fmaxf(v[2], v[3]));
      mx = fmaxf(mx, __shfl_xor(mx, 1));
      mx = fmaxf(mx, __shfl_xor(mx, 2));
      mx = fmaxf(mx, __shfl_xor(mx, 4));
      mx = fmaxf(mx, __shfl_xor(mx, 8));
      if (mx > rm[r]) {                           // rescale only when max grows
        const float corr = __expf(rm[r] - mx);
        rl[r] *= corr;
        #pragma unroll
        for (int df = 0; df < 8; ++df) acc[df][r] *= corr;
        rm[r] = mx;
      }
      float sum = 0.f;
      #pragma unroll
      for (int cf = 0; cf < 4; ++cf) { p[r][cf] = __expf(v[cf] - rm[r]); sum += p[r][cf]; }
      sum += __shfl_xor(sum, 1);
      sum += __shfl_xor(sum, 2);
      sum += __shfl_xor(sum, 4);
      sum += __shfl_xor(sum, 8);
      rl[r] += sum;
    }

    // -- P -> LDS (per-wave region, stride 72), re-read as A-fragments --
    #pragma unroll
    for (int r = 0; r < 4; ++r)
      #pragma unroll
      for (int cf = 0; cf < 4; ++cf)
        Pl[w][(g * 4 + r) * 72 + cf * 16 + tl] = f2bf(p[r][cf]);
    const bf8 pf0 = *(const bf8*)&Pl[w][tl * 72 + g * 8];        // k = 0..31
    const bf8 pf1 = *(const bf8*)&Pl[w][tl * 72 + 32 + g * 8];   // k = 32..63

    // -- PV: acc(16x128) += P(16x64) x V(64x128) --
    __builtin_amdgcn_s_setprio(1);
    #pragma unroll
    for (int df = 0; df < 8; ++df) {
      const int vrow = (df * 16 + tl) * 64;
      const bf8 v0 = *(const bf8*)&Vs[cur][vrow + ((g ^ (tl & 7)) * 8)];
      const bf8 v1 = *(const bf8*)&Vs[cur][vrow + (((4 + g) ^ (tl & 7)) * 8)];
      acc[df] = __builtin_amdgcn_mfma_f32_16x16x32_bf16(pf0, v0, acc[df], 0, 0, 0);
      acc[df] = __builtin_amdgcn_mfma_f32_16x16x32_bf16(pf1, v1, acc[df], 0, 0, 0);
    }
    __builtin_amdgcn_s_setprio(0);

    __builtin_amdgcn_s_barrier();                // done reading buf before restage
  }
  #undef STAGE_TILE

  // -- normalize + store ctx[b, q, hq*128 + d] --
  #pragma unroll
  for (int r = 0; r < 4; ++r) {
    const float inv = 1.0f / rl[r];
    const size_t ob = ((size_t)(b * 2048 + qrow0 + g * 4 + r)) * 4096 + hq * 128 + tl;
    #pragma unroll
    for (int df = 0; df < 8; ++df)
      O[ob + df * 16] = f2bf(acc[df][r] * inv);
  }
}

// ---------- launch ----------
extern "C" void kernel_launch(void* const* d_in, const int* in_sizes, int n_in,
                              void* d_out, int out_size, void* d_ws, size_t ws_size,
                              hipStream_t stream) {
  const float* hs   = (const float*)d_in[0];
  const float* cosT = (const float*)d_in[2];
  const float* sinT = (const float*)d_in[3];
  const float* Wq   = (const float*)d_in[4];
  const float* Wk   = (const float*)d_in[5];
  const float* Wv   = (const float*)d_in[6];
  const float* Wo   = (const float*)d_in[7];

  // ---- workspace liveness plan (peak 83,886,080 B = proven bound) ----
  // hsb  = d_out [4096,8192] bf16 (67,108,864 B exact)  live: cvt -> V gemm
  // [ 0M,32M) qb    [4096,4096] bf16   live: Q gemms -> flash; then wobf
  // [32M,40M) kbuf  [4096,1024] bf16   live: K gemm -> flash
  // [40M,48M) vbuf  [4096,1024] bf16   live: V gemm -> vtrans
  // [48M,80M) wq_half [2048,8192] bf16 live: cvt -> its half-gemm (x2, serial)
  // [48M,64M) wkvbf [1024,8192] bf16   live: cvt -> K/V gemm (serial reuse)
  // [72M,80M) vt    [16,128,2048] bf16 live: vtrans -> flash
  // [40M,72M) ctx   [4096,4096] bf16   live: flash -> Wo gemm (over dead bufs)
  // final gemm writes d_out f32 (hsb dead after V gemm)
  char* ws = (char*)d_ws;
  uint16_t* qb    = (uint16_t*)(ws);
  uint16_t* kbuf  = (uint16_t*)(ws + 33554432);
  uint16_t* vbuf  = (uint16_t*)(ws + 41943040);
  uint16_t* whalf = (uint16_t*)(ws + 50331648);   // Wq halves / Wk / Wv (serial)
  uint16_t* vt    = (uint16_t*)(ws + 75497472);
  uint16_t* ctx   = (uint16_t*)(ws + 41943040);
  uint16_t* hsb   = (uint16_t*)d_out;
  uint16_t* wobf  = qb;

  const dim3 blk(256);

  // 1) hs f32 -> bf16 (once)
  eagle3_cvt<<<dim3(2048), blk, 0, stream>>>(hs, hsb, 4194304);

  // 2) Q projection in two N=2048 halves through one 32 MiB weight buffer
  eagle3_cvt<<<dim3(2048), blk, 0, stream>>>(Wq, whalf, 2097152);
  eagle3_gemm2<false><<<dim3(16, 32), blk, 0, stream>>>(
      hsb, whalf, (void*)qb, 8192, 8192, 8192, 4096);
  eagle3_cvt<<<dim3(2048), blk, 0, stream>>>(Wq + 16777216, whalf, 2097152);
  eagle3_gemm2<false><<<dim3(16, 32), blk, 0, stream>>>(
      hsb, whalf, (void*)(qb + 2048), 8192, 8192, 8192, 4096);

  // 3) K and V projections (weight buffer reused serially)
  eagle3_cvt<<<dim3(2048), blk, 0, stream>>>(Wk, whalf, 1048576);
  eagle3_gemm2<false><<<dim3(8, 32), blk, 0, stream>>>(
      hsb, whalf, (void*)kbuf, 8192, 8192, 8192, 1024);
  eagle3_cvt<<<dim3(2048), blk, 0, stream>>>(Wv, whalf, 1048576);
  eagle3_gemm2<false><<<dim3(8, 32), blk, 0, stream>>>(
      hsb, whalf, (void*)vbuf, 8192, 8192, 8192, 1024);

  // 4) RoPE + V transpose
  eagle3_rope<<<dim3(32768), blk, 0, stream>>>(qb, cosT, sinT, 32, 4096, 8388608);
  eagle3_rope<<<dim3(8192), blk, 0, stream>>>(kbuf, cosT, sinT, 8, 1024, 2097152);
  eagle3_vtrans<<<dim3(32, 16), blk, 0, stream>>>(vbuf, vt);

  // 5) causal GQA flash attention -> ctx
  eagle3_flash4<<<dim3(32, 32, 2), blk, 0, stream>>>(qb, kbuf, vt, ctx);

  // 6) output projection: out = ctx * Wo^T (f32 out over dead hsb)
  eagle3_cvt<<<dim3(2048), blk, 0, stream>>>(Wo, wobf, 2097152);
  eagle3_gemm2<true><<<dim3(32, 32), blk, 0, stream>>>(
      ctx, wobf, d_out, 4096, 4096, 4096, 4096);
}

// Round 7
// 1025.948 us; speedup vs baseline: 2.5144x; 1.1907x over previous
//
#include <hip/hip_runtime.h>
#include <stdint.h>

// ---------- common types / helpers ----------
typedef __attribute__((ext_vector_type(8))) short bf8;   // 8 x bf16 (4 VGPRs)
typedef __attribute__((ext_vector_type(4))) float f4;    // MFMA accumulator

__device__ __forceinline__ float bf2f(uint16_t u) {
  union { unsigned i; float f; } v; v.i = ((unsigned)u) << 16; return v.f;
}
__device__ __forceinline__ uint16_t f2bf(float f) {
  union { float f; unsigned i; } v; v.f = f;
  unsigned r = v.i + 0x7fffu + ((v.i >> 16) & 1u);   // RTNE
  return (uint16_t)(r >> 16);
}
__device__ __forceinline__ bf8 cvt8(float4 a, float4 b) {
  bf8 r;
  r[0]=(short)f2bf(a.x); r[1]=(short)f2bf(a.y); r[2]=(short)f2bf(a.z); r[3]=(short)f2bf(a.w);
  r[4]=(short)f2bf(b.x); r[5]=(short)f2bf(b.y); r[6]=(short)f2bf(b.z); r[7]=(short)f2bf(b.w);
  return r;
}

// async global->LDS, 16B per lane, wave-uniform LDS base + lane*16
__device__ __forceinline__ void gload_lds16(const void* g, void* l) {
  __builtin_amdgcn_global_load_lds(
      (const __attribute__((address_space(1))) uint32_t*)(uintptr_t)g,
      (__attribute__((address_space(3))) uint32_t*)(uint32_t)(uintptr_t)l,
      16, 0, 0);
}

// ---------- f32 -> bf16 bulk convert ----------
__global__ __launch_bounds__(256)
void eagle3_cvt(const float* __restrict__ src, uint16_t* __restrict__ dst, int n8)
{
  int i = blockIdx.x * 256 + threadIdx.x;
  const int stride = gridDim.x * 256;
  for (; i < n8; i += stride) {
    const float4 a = ((const float4*)src)[i * 2];
    const float4 b = ((const float4*)src)[i * 2 + 1];
    ((bf8*)dst)[i] = cvt8(a, b);
  }
}

// ---------- GEMM v2 (128x128, m97 structure) : C = A * B^T, bf16 ----------
template<bool OF32>
__global__ __launch_bounds__(256)
void eagle3_gemm2(const uint16_t* __restrict__ Ap, const uint16_t* __restrict__ Bp,
                  void* __restrict__ Cp, int K, int lda, int ldb, int ldc)
{
  __shared__ __align__(16) uint16_t As[128 * 32];
  __shared__ __align__(16) uint16_t Bs[128 * 32];

  const int nwg = gridDim.x * gridDim.y;
  const int bid = blockIdx.y * gridDim.x + blockIdx.x;
  const int qq = nwg >> 3;
  const int sw = (bid & 7) * qq + (bid >> 3);
  const int bx = sw % gridDim.x, by = sw / gridDim.x;
  const int m0 = by * 128, n0 = bx * 128;

  const int tid = threadIdx.x, lane = tid & 63, w = tid >> 6;
  const int tl = lane & 15, g = lane >> 4;
  const int wr = (w >> 1) * 64, wc = (w & 1) * 64;

  f4 acc[4][4] = {};

  for (int k0 = 0; k0 < K; k0 += 32) {
    __syncthreads();
    #pragma unroll
    for (int i = 0; i < 2; ++i) {
      const int o = (w * 2 + i) * 1024 + lane * 16;
      const int r = o >> 6;
      const int u = (((o >> 4) & 3) ^ ((r >> 1) & 3)) * 8;
      gload_lds16(Ap + (size_t)(m0 + r) * lda + k0 + u, &As[(w * 2 + i) * 512]);
    }
    #pragma unroll
    for (int i = 0; i < 2; ++i) {
      const int o = (w * 2 + i) * 1024 + lane * 16;
      const int r = o >> 6;
      const int u = (((o >> 4) & 3) ^ ((r >> 1) & 3)) * 8;
      gload_lds16(Bp + (size_t)(n0 + r) * ldb + k0 + u, &Bs[(w * 2 + i) * 512]);
    }
    __syncthreads();

    bf8 af[4], bf_[4];
    #pragma unroll
    for (int i = 0; i < 4; ++i) {
      const int ar = wr + i * 16 + tl;
      const int br = wc + i * 16 + tl;
      af[i]  = *(const bf8*)&As[ar * 32 + ((g ^ ((ar >> 1) & 3)) * 8)];
      bf_[i] = *(const bf8*)&Bs[br * 32 + ((g ^ ((br >> 1) & 3)) * 8)];
    }
    #pragma unroll
    for (int mi = 0; mi < 4; ++mi)
      #pragma unroll
      for (int ni = 0; ni < 4; ++ni)
        acc[mi][ni] = __builtin_amdgcn_mfma_f32_16x16x32_bf16(af[mi], bf_[ni], acc[mi][ni], 0, 0, 0);
  }

  #pragma unroll
  for (int mi = 0; mi < 4; ++mi) {
    #pragma unroll
    for (int r = 0; r < 4; ++r) {
      const int row = m0 + wr + mi * 16 + g * 4 + r;
      #pragma unroll
      for (int ni = 0; ni < 4; ++ni) {
        const int col = n0 + wc + ni * 16 + tl;
        const float v = acc[mi][ni][r];
        if constexpr (OF32) ((float*)Cp)[(size_t)row * ldc + col] = v;
        else                ((uint16_t*)Cp)[(size_t)row * ldc + col] = f2bf(v);
      }
    }
  }
}

// ---------- GEMM v3 (256x256, 4-deep ring pipeline) : C = A * B^T, bf16 ----
// BK=32, 512 threads (8 waves = 2Mx4N, each 128x64 out, acc 8x4).
// LDS: 4 ring slots x (A 16KB + B 16KB) = 128KB. Iteration t computes slot
// t%4 while tiles t+1..t+3 are in DMA flight; each iteration issues tile
// t+3 (4 x global_load_lds per thread) and waits vmcnt(8) only -> loads span
// barriers, never drained (T3+T4). One s_barrier per K-step: writes target
// slot (t+3)%4 == (t-1)%4, whose reads completed before this barrier.
// [256][32] bf16 rows = 64B -> b128 fragment reads are bank-balanced, no swz.
template<bool OF32>
__global__ __launch_bounds__(512, 2)
void eagle3_gemm3(const uint16_t* __restrict__ Ap, const uint16_t* __restrict__ Bp,
                  void* __restrict__ Cp, int K, int lda, int ldb, int ldc)
{
  __shared__ __align__(16) uint16_t As[4][256 * 32];
  __shared__ __align__(16) uint16_t Bs[4][256 * 32];

  const int nwg = gridDim.x * gridDim.y;
  const int bid = blockIdx.y * gridDim.x + blockIdx.x;
  const int qq = nwg >> 3;
  const int sw = (bid & 7) * qq + (bid >> 3);
  const int bx = sw % gridDim.x, by = sw / gridDim.x;
  const int m0 = by * 256, n0 = bx * 256;

  const int tid = threadIdx.x, lane = tid & 63;
  const int tl = lane & 15, g = lane >> 4;
  const int w = tid >> 6;                 // 0..7
  const int wm = w >> 2, wn = w & 3;      // 2 x 4
  const int wr = wm * 128, wc = wn * 64;

  f4 acc[8][4] = {};
  const int NT = K >> 5;

  // thread t stages 16B chunks j = t and t+512 of each 256x32 tile:
  // chunk j -> row j>>2, 16B slot j&3 (cols (j&3)*8 .. +8). LDS linear.
  #define STAGE3(tt)                                                            \
    {                                                                           \
      const int kk = (tt) << 5;                                                 \
      const int bsel_ = (tt) & 3;                                               \
      gload_lds16(Ap + (size_t)(m0 + (tid >> 2)) * lda + kk + (tid & 3) * 8,    \
                  &As[bsel_][tid * 8]);                                         \
      gload_lds16(Ap + (size_t)(m0 + 128 + (tid >> 2)) * lda + kk + (tid & 3) * 8, \
                  &As[bsel_][(tid + 512) * 8]);                                 \
      gload_lds16(Bp + (size_t)(n0 + (tid >> 2)) * ldb + kk + (tid & 3) * 8,    \
                  &Bs[bsel_][tid * 8]);                                         \
      gload_lds16(Bp + (size_t)(n0 + 128 + (tid >> 2)) * ldb + kk + (tid & 3) * 8, \
                  &Bs[bsel_][(tid + 512) * 8]);                                 \
    }

  STAGE3(0);
  if (NT > 1) STAGE3(1);
  if (NT > 2) STAGE3(2);

  for (int t = 0; t < NT; ++t) {
    // wait for tile t only: tiles t+1, t+2 (4 loads each) may stay in flight
    if (t + 2 < NT)      asm volatile("s_waitcnt vmcnt(8)" ::: "memory");
    else if (t + 1 < NT) asm volatile("s_waitcnt vmcnt(4)" ::: "memory");
    else                 asm volatile("s_waitcnt vmcnt(0)" ::: "memory");
    __builtin_amdgcn_sched_barrier(0);
    __builtin_amdgcn_s_barrier();          // tile t visible; slot t-1 reads done
    __builtin_amdgcn_sched_barrier(0);

    if (t + 3 < NT) STAGE3(t + 3);         // -> slot (t+3)%4 == (t-1)%4, safe

    const int bsel = t & 3;
    bf8 af[8], bfr[4];
    #pragma unroll
    for (int i = 0; i < 8; ++i)
      af[i] = *(const bf8*)&As[bsel][(wr + i * 16 + tl) * 32 + g * 8];
    #pragma unroll
    for (int i = 0; i < 4; ++i)
      bfr[i] = *(const bf8*)&Bs[bsel][(wc + i * 16 + tl) * 32 + g * 8];

    __builtin_amdgcn_s_setprio(1);
    #pragma unroll
    for (int mi = 0; mi < 8; ++mi)
      #pragma unroll
      for (int ni = 0; ni < 4; ++ni)
        acc[mi][ni] = __builtin_amdgcn_mfma_f32_16x16x32_bf16(af[mi], bfr[ni], acc[mi][ni], 0, 0, 0);
    __builtin_amdgcn_s_setprio(0);
  }
  #undef STAGE3

  // epilogue: C/D layout col=lane&15, row=(lane>>4)*4+reg
  #pragma unroll
  for (int mi = 0; mi < 8; ++mi) {
    #pragma unroll
    for (int r = 0; r < 4; ++r) {
      const int row = m0 + wr + mi * 16 + g * 4 + r;
      #pragma unroll
      for (int ni = 0; ni < 4; ++ni) {
        const int col = n0 + wc + ni * 16 + tl;
        const float v = acc[mi][ni][r];
        if constexpr (OF32) ((float*)Cp)[(size_t)row * ldc + col] = v;
        else                ((uint16_t*)Cp)[(size_t)row * ldc + col] = f2bf(v);
      }
    }
  }
}

// ---------- RoPE (in-place on bf16, pairs (d, d+64)) ----------
__global__ __launch_bounds__(256)
void eagle3_rope(uint16_t* __restrict__ x, const float* __restrict__ cs,
                 const float* __restrict__ sn, int nh, int rowlen, int total)
{
  int id = blockIdx.x * 256 + threadIdx.x;
  if (id >= total) return;
  int d = id & 63;
  int t = id >> 6;
  int head = t & (nh - 1);
  int row = t / nh;
  int s = row & 2047;
  size_t base = (size_t)row * rowlen + head * 128;
  float c = cs[s * 128 + d], si = sn[s * 128 + d];
  float x1 = bf2f(x[base + d]), x2 = bf2f(x[base + d + 64]);
  x[base + d]      = f2bf(x1 * c - x2 * si);
  x[base + d + 64] = f2bf(x2 * c + x1 * si);
}

// ---------- V transpose: [b,t,h,d] -> [b,h,d,t] ----------
__global__ __launch_bounds__(256)
void eagle3_vtrans(const uint16_t* __restrict__ V, uint16_t* __restrict__ Vt)
{
  __shared__ uint16_t T[64 * 136];
  const int tid = threadIdx.x;
  const int t0 = blockIdx.x * 64;
  const int bh = blockIdx.y;
  const int b = bh >> 3, h = bh & 7;
  {
    const int r = tid >> 2, c0 = (tid & 3) * 32;
    const uint16_t* src = V + (size_t)(b * 2048 + t0 + r) * 1024 + h * 128 + c0;
    #pragma unroll
    for (int j = 0; j < 4; ++j)
      *(bf8*)&T[r * 136 + c0 + j * 8] = *(const bf8*)(src + j * 8);
  }
  __syncthreads();
  {
    const int d = tid >> 1, tc = (tid & 1) * 32;
    uint16_t* dst = Vt + ((size_t)bh * 128 + d) * 2048 + t0 + tc;
    #pragma unroll
    for (int cc = 0; cc < 4; ++cc) {
      bf8 v;
      #pragma unroll
      for (int j = 0; j < 8; ++j) v[j] = T[(tc + cc * 8 + j) * 136 + d];
      *(bf8*)&dst[cc * 8] = v;
    }
  }
}

// ---------- causal GQA flash attention v4 (unchanged from round 6) ----------
__global__ __launch_bounds__(256, 2)
void eagle3_flash4(const uint16_t* __restrict__ Q, const uint16_t* __restrict__ Kt,
                   const uint16_t* __restrict__ Vt, uint16_t* __restrict__ O)
{
  __shared__ __align__(16) uint16_t Ks[2][64 * 128];
  __shared__ __align__(16) uint16_t Vs[2][128 * 64];
  __shared__ __align__(16) uint16_t Pl[4][16 * 72];

  const int tid = threadIdx.x, lane = tid & 63, w = tid >> 6;
  const int tl = lane & 15, g = lane >> 4;

  const int bid = (int)blockIdx.x + ((int)blockIdx.y << 5) + ((int)blockIdx.z << 10);
  const int xcd = bid & 7, idx = bid >> 3;
  const int grp = xcd * 2 + (idx >> 7);
  const int j   = idx & 127;
  const int b = grp >> 3, hkv = grp & 7;
  const int hq = hkv * 4 + (j & 3);
  const int qt = 31 - (j >> 2);
  const int qrow0 = qt * 64 + w * 16;
  const int ntb = qt + 1;

  bf8 qf[4];
  {
    const uint16_t* qp = Q + ((size_t)(b * 2048 + qrow0 + tl)) * 4096 + hq * 128 + g * 8;
    #pragma unroll
    for (int kb = 0; kb < 4; ++kb) qf[kb] = *(const bf8*)(qp + kb * 32);
  }

  const uint16_t* Kbase = Kt + (size_t)b * 2048 * 1024 + hkv * 128;
  const uint16_t* Vtb   = Vt + ((size_t)(b * 8 + hkv) * 128) * 2048;

  f4 acc[8] = {};
  float rm[4] = {-3e38f, -3e38f, -3e38f, -3e38f};
  float rl[4] = {0.f, 0.f, 0.f, 0.f};
  const float scale = 0.08838834764831845f;

  #define STAGE_TILE(buf, t0s)                                                   \
    {                                                                            \
      _Pragma("unroll")                                                          \
      for (int i = 0; i < 4; ++i) {                                              \
        const int f = i * 256 + tid;                                             \
        const int r = f >> 4, c = f & 15;                                        \
        gload_lds16(Kbase + (size_t)((t0s) + r) * 1024 + ((c ^ (r & 7)) * 8),    \
                    &Ks[buf][(i * 256 + w * 64) * 8]);                           \
      }                                                                          \
      _Pragma("unroll")                                                          \
      for (int i = 0; i < 4; ++i) {                                              \
        const int f = i * 256 + tid;                                             \
        const int d = f >> 3, c = f & 7;                                         \
        gload_lds16(Vtb + (size_t)d * 2048 + (t0s) + ((c ^ (d & 7)) * 8),        \
                    &Vs[buf][(i * 256 + w * 64) * 8]);                           \
      }                                                                          \
    }

  STAGE_TILE(0, 0);

  for (int tb = 0; tb < ntb; ++tb) {
    const int cur = tb & 1;
    const int t0 = tb * 64;

    if (tb + 1 < ntb) {
      STAGE_TILE(cur ^ 1, t0 + 64);
      asm volatile("s_waitcnt vmcnt(8)" ::: "memory");
    } else {
      asm volatile("s_waitcnt vmcnt(0)" ::: "memory");
    }
    __builtin_amdgcn_sched_barrier(0);
    __builtin_amdgcn_s_barrier();

    f4 s[4] = {};
    __builtin_amdgcn_s_setprio(1);
    #pragma unroll
    for (int cf = 0; cf < 4; ++cf) {
      #pragma unroll
      for (int kb = 0; kb < 4; ++kb) {
        const bf8 kf = *(const bf8*)&Ks[cur][(cf * 16 + tl) * 128 +
                                            (((kb * 4 + g) ^ (tl & 7)) * 8)];
        s[cf] = __builtin_amdgcn_mfma_f32_16x16x32_bf16(qf[kb], kf, s[cf], 0, 0, 0);
      }
    }
    __builtin_amdgcn_s_setprio(0);

    float p[4][4];
    #pragma unroll
    for (int r = 0; r < 4; ++r) {
      const int qg = qrow0 + g * 4 + r;
      float v[4];
      #pragma unroll
      for (int cf = 0; cf < 4; ++cf) {
        v[cf] = s[cf][r] * scale;
        if (t0 + cf * 16 + tl > qg) v[cf] = -1e30f;
      }
      float mx = fmaxf(fmaxf(v[0], v[1]), fmaxf(v[2], v[3]));
      mx = fmaxf(mx, __shfl_xor(mx, 1));
      mx = fmaxf(mx, __shfl_xor(mx, 2));
      mx = fmaxf(mx, __shfl_xor(mx, 4));
      mx = fmaxf(mx, __shfl_xor(mx, 8));
      if (mx > rm[r]) {
        const float corr = __expf(rm[r] - mx);
        rl[r] *= corr;
        #pragma unroll
        for (int df = 0; df < 8; ++df) acc[df][r] *= corr;
        rm[r] = mx;
      }
      float sum = 0.f;
      #pragma unroll
      for (int cf = 0; cf < 4; ++cf) { p[r][cf] = __expf(v[cf] - rm[r]); sum += p[r][cf]; }
      sum += __shfl_xor(sum, 1);
      sum += __shfl_xor(sum, 2);
      sum += __shfl_xor(sum, 4);
      sum += __shfl_xor(sum, 8);
      rl[r] += sum;
    }

    #pragma unroll
    for (int r = 0; r < 4; ++r)
      #pragma unroll
      for (int cf = 0; cf < 4; ++cf)
        Pl[w][(g * 4 + r) * 72 + cf * 16 + tl] = f2bf(p[r][cf]);
    const bf8 pf0 = *(const bf8*)&Pl[w][tl * 72 + g * 8];
    const bf8 pf1 = *(const bf8*)&Pl[w][tl * 72 + 32 + g * 8];

    __builtin_amdgcn_s_setprio(1);
    #pragma unroll
    for (int df = 0; df < 8; ++df) {
      const int vrow = (df * 16 + tl) * 64;
      const bf8 v0 = *(const bf8*)&Vs[cur][vrow + ((g ^ (tl & 7)) * 8)];
      const bf8 v1 = *(const bf8*)&Vs[cur][vrow + (((4 + g) ^ (tl & 7)) * 8)];
      acc[df] = __builtin_amdgcn_mfma_f32_16x16x32_bf16(pf0, v0, acc[df], 0, 0, 0);
      acc[df] = __builtin_amdgcn_mfma_f32_16x16x32_bf16(pf1, v1, acc[df], 0, 0, 0);
    }
    __builtin_amdgcn_s_setprio(0);

    __builtin_amdgcn_s_barrier();
  }
  #undef STAGE_TILE

  #pragma unroll
  for (int r = 0; r < 4; ++r) {
    const float inv = 1.0f / rl[r];
    const size_t ob = ((size_t)(b * 2048 + qrow0 + g * 4 + r)) * 4096 + hq * 128 + tl;
    #pragma unroll
    for (int df = 0; df < 8; ++df)
      O[ob + df * 16] = f2bf(acc[df][r] * inv);
  }
}

// ---------- launch ----------
extern "C" void kernel_launch(void* const* d_in, const int* in_sizes, int n_in,
                              void* d_out, int out_size, void* d_ws, size_t ws_size,
                              hipStream_t stream) {
  const float* hs   = (const float*)d_in[0];
  const float* cosT = (const float*)d_in[2];
  const float* sinT = (const float*)d_in[3];
  const float* Wq   = (const float*)d_in[4];
  const float* Wk   = (const float*)d_in[5];
  const float* Wv   = (const float*)d_in[6];
  const float* Wo   = (const float*)d_in[7];

  // ---- workspace liveness ----
  // hsb = d_out [4096,8192] bf16 (64MB exact)   live: cvt -> V gemm
  // [ 0M,32M) qb     live: Q gemm -> flash; then wobf
  // [32M,40M) kbuf   live: K gemm -> flash
  // [40M,48M) vbuf   live: V gemm -> vtrans
  // [48M,..)  weights (serial): Wq full 64MB (if ws>=112M) else 32MB halves;
  //           then Wk/Wv 16MB each
  // [72M,80M) vt     live: vtrans -> flash (over dead weight region)
  // [40M,72M) ctx    live: flash -> Wo gemm (over dead bufs)
  char* ws = (char*)d_ws;
  uint16_t* qb    = (uint16_t*)(ws);
  uint16_t* kbuf  = (uint16_t*)(ws + 33554432);
  uint16_t* vbuf  = (uint16_t*)(ws + 41943040);
  uint16_t* whalf = (uint16_t*)(ws + 50331648);
  uint16_t* vt    = (uint16_t*)(ws + 75497472);
  uint16_t* ctx   = (uint16_t*)(ws + 41943040);
  uint16_t* hsb   = (uint16_t*)d_out;
  uint16_t* wobf  = qb;

  const dim3 blk(256);
  const bool fullq = (ws_size >= (size_t)117440512);   // 112 MiB

  // 1) hs f32 -> bf16 (once)
  eagle3_cvt<<<dim3(2048), blk, 0, stream>>>(hs, hsb, 4194304);

  // 2) Q projection
  if (fullq) {
    eagle3_cvt<<<dim3(2048), blk, 0, stream>>>(Wq, whalf, 4194304);   // 64MB bf16
    eagle3_gemm3<false><<<dim3(16, 16), dim3(512), 0, stream>>>(
        hsb, whalf, (void*)qb, 8192, 8192, 8192, 4096);
  } else {
    eagle3_cvt<<<dim3(2048), blk, 0, stream>>>(Wq, whalf, 2097152);
    eagle3_gemm2<false><<<dim3(16, 32), blk, 0, stream>>>(
        hsb, whalf, (void*)qb, 8192, 8192, 8192, 4096);
    eagle3_cvt<<<dim3(2048), blk, 0, stream>>>(Wq + 16777216, whalf, 2097152);
    eagle3_gemm2<false><<<dim3(16, 32), blk, 0, stream>>>(
        hsb, whalf, (void*)(qb + 2048), 8192, 8192, 8192, 4096);
  }

  // 3) K and V projections (weight buffer reused serially; 128^2 kernel keeps
  //    grid at 256 blocks for N=1024)
  eagle3_cvt<<<dim3(2048), blk, 0, stream>>>(Wk, whalf, 1048576);
  eagle3_gemm2<false><<<dim3(8, 32), blk, 0, stream>>>(
      hsb, whalf, (void*)kbuf, 8192, 8192, 8192, 1024);
  eagle3_cvt<<<dim3(2048), blk, 0, stream>>>(Wv, whalf, 1048576);
  eagle3_gemm2<false><<<dim3(8, 32), blk, 0, stream>>>(
      hsb, whalf, (void*)vbuf, 8192, 8192, 8192, 1024);

  // 4) RoPE + V transpose
  eagle3_rope<<<dim3(32768), blk, 0, stream>>>(qb, cosT, sinT, 32, 4096, 8388608);
  eagle3_rope<<<dim3(8192), blk, 0, stream>>>(kbuf, cosT, sinT, 8, 1024, 2097152);
  eagle3_vtrans<<<dim3(32, 16), blk, 0, stream>>>(vbuf, vt);

  // 5) causal GQA flash attention -> ctx
  eagle3_flash4<<<dim3(32, 32, 2), blk, 0, stream>>>(qb, kbuf, vt, ctx);

  // 6) output projection: out = ctx * Wo^T (f32 out over dead hsb)
  eagle3_cvt<<<dim3(2048), blk, 0, stream>>>(Wo, wobf, 2097152);
  eagle3_gemm3<true><<<dim3(16, 16), dim3(512), 0, stream>>>(
      ctx, wobf, d_out, 4096, 4096, 4096, 4096);
}

// Round 8
// 1004.896 us; speedup vs baseline: 2.5671x; 1.0209x over previous
//
#include <hip/hip_runtime.h>
#include <stdint.h>

// ---------- common types / helpers ----------
typedef __attribute__((ext_vector_type(8))) short bf8;   // 8 x bf16 (4 VGPRs)
typedef __attribute__((ext_vector_type(4))) float f4;    // MFMA accumulator

__device__ __forceinline__ float bf2f(uint16_t u) {
  union { unsigned i; float f; } v; v.i = ((unsigned)u) << 16; return v.f;
}
__device__ __forceinline__ uint16_t f2bf(float f) {
  union { float f; unsigned i; } v; v.f = f;
  unsigned r = v.i + 0x7fffu + ((v.i >> 16) & 1u);   // RTNE
  return (uint16_t)(r >> 16);
}
__device__ __forceinline__ bf8 cvt8(float4 a, float4 b) {
  bf8 r;
  r[0]=(short)f2bf(a.x); r[1]=(short)f2bf(a.y); r[2]=(short)f2bf(a.z); r[3]=(short)f2bf(a.w);
  r[4]=(short)f2bf(b.x); r[5]=(short)f2bf(b.y); r[6]=(short)f2bf(b.z); r[7]=(short)f2bf(b.w);
  return r;
}
// packed f32x2 -> bf16x2 (RNE); dst.lo = cvt(a), dst.hi = cvt(b)  [T12 recipe]
__device__ __forceinline__ uint32_t cvtpk(float a, float b) {
  uint32_t r;
  asm("v_cvt_pk_bf16_f32 %0, %1, %2" : "=v"(r) : "v"(a), "v"(b));
  return r;
}

// async global->LDS, 16B per lane, wave-uniform LDS base + lane*16
__device__ __forceinline__ void gload_lds16(const void* g, void* l) {
  __builtin_amdgcn_global_load_lds(
      (const __attribute__((address_space(1))) uint32_t*)(uintptr_t)g,
      (__attribute__((address_space(3))) uint32_t*)(uint32_t)(uintptr_t)l,
      16, 0, 0);
}

// ---------- f32 -> bf16 bulk convert ----------
__global__ __launch_bounds__(256)
void eagle3_cvt(const float* __restrict__ src, uint16_t* __restrict__ dst, int n8)
{
  int i = blockIdx.x * 256 + threadIdx.x;
  const int stride = gridDim.x * 256;
  for (; i < n8; i += stride) {
    const float4 a = ((const float4*)src)[i * 2];
    const float4 b = ((const float4*)src)[i * 2 + 1];
    ((bf8*)dst)[i] = cvt8(a, b);
  }
}

// ---------- GEMM v2 (128x128, m97 structure) : C = A * B^T, bf16 ----------
template<bool OF32>
__global__ __launch_bounds__(256)
void eagle3_gemm2(const uint16_t* __restrict__ Ap, const uint16_t* __restrict__ Bp,
                  void* __restrict__ Cp, int K, int lda, int ldb, int ldc)
{
  __shared__ __align__(16) uint16_t As[128 * 32];
  __shared__ __align__(16) uint16_t Bs[128 * 32];

  const int nwg = gridDim.x * gridDim.y;
  const int bid = blockIdx.y * gridDim.x + blockIdx.x;
  const int qq = nwg >> 3;
  const int sw = (bid & 7) * qq + (bid >> 3);
  const int bx = sw % gridDim.x, by = sw / gridDim.x;
  const int m0 = by * 128, n0 = bx * 128;

  const int tid = threadIdx.x, lane = tid & 63, w = tid >> 6;
  const int tl = lane & 15, g = lane >> 4;
  const int wr = (w >> 1) * 64, wc = (w & 1) * 64;

  f4 acc[4][4] = {};

  for (int k0 = 0; k0 < K; k0 += 32) {
    __syncthreads();
    #pragma unroll
    for (int i = 0; i < 2; ++i) {
      const int o = (w * 2 + i) * 1024 + lane * 16;
      const int r = o >> 6;
      const int u = (((o >> 4) & 3) ^ ((r >> 1) & 3)) * 8;
      gload_lds16(Ap + (size_t)(m0 + r) * lda + k0 + u, &As[(w * 2 + i) * 512]);
    }
    #pragma unroll
    for (int i = 0; i < 2; ++i) {
      const int o = (w * 2 + i) * 1024 + lane * 16;
      const int r = o >> 6;
      const int u = (((o >> 4) & 3) ^ ((r >> 1) & 3)) * 8;
      gload_lds16(Bp + (size_t)(n0 + r) * ldb + k0 + u, &Bs[(w * 2 + i) * 512]);
    }
    __syncthreads();

    bf8 af[4], bf_[4];
    #pragma unroll
    for (int i = 0; i < 4; ++i) {
      const int ar = wr + i * 16 + tl;
      const int br = wc + i * 16 + tl;
      af[i]  = *(const bf8*)&As[ar * 32 + ((g ^ ((ar >> 1) & 3)) * 8)];
      bf_[i] = *(const bf8*)&Bs[br * 32 + ((g ^ ((br >> 1) & 3)) * 8)];
    }
    #pragma unroll
    for (int mi = 0; mi < 4; ++mi)
      #pragma unroll
      for (int ni = 0; ni < 4; ++ni)
        acc[mi][ni] = __builtin_amdgcn_mfma_f32_16x16x32_bf16(af[mi], bf_[ni], acc[mi][ni], 0, 0, 0);
  }

  #pragma unroll
  for (int mi = 0; mi < 4; ++mi) {
    #pragma unroll
    for (int r = 0; r < 4; ++r) {
      const int row = m0 + wr + mi * 16 + g * 4 + r;
      #pragma unroll
      for (int ni = 0; ni < 4; ++ni) {
        const int col = n0 + wc + ni * 16 + tl;
        const float v = acc[mi][ni][r];
        if constexpr (OF32) ((float*)Cp)[(size_t)row * ldc + col] = v;
        else                ((uint16_t*)Cp)[(size_t)row * ldc + col] = f2bf(v);
      }
    }
  }
}

// ---------- GEMM v3 (256x256, 4-deep ring pipeline) : C = A * B^T, bf16 ----
// BK=32, 512 threads (8 waves = 2Mx4N, each 128x64 out, acc 8x4).
// Both-sides XOR chunk swizzle (c ^= (row>>1)&3): pre-swizzled global source,
// linear LDS dest, same XOR on the fragment read -> 8-way conflict becomes
// free 2-way (gemm2's proven scheme; round-7 counter showed 2.5e7 conflicts
// without it). Counted vmcnt keeps 2 tiles in DMA flight across barriers.
template<bool OF32>
__global__ __launch_bounds__(512, 2)
void eagle3_gemm3(const uint16_t* __restrict__ Ap, const uint16_t* __restrict__ Bp,
                  void* __restrict__ Cp, int K, int lda, int ldb, int ldc)
{
  __shared__ __align__(16) uint16_t As[4][256 * 32];
  __shared__ __align__(16) uint16_t Bs[4][256 * 32];

  const int nwg = gridDim.x * gridDim.y;
  const int bid = blockIdx.y * gridDim.x + blockIdx.x;
  const int qq = nwg >> 3;
  const int sw = (bid & 7) * qq + (bid >> 3);
  const int bx = sw % gridDim.x, by = sw / gridDim.x;
  const int m0 = by * 256, n0 = bx * 256;

  const int tid = threadIdx.x, lane = tid & 63;
  const int tl = lane & 15, g = lane >> 4;
  const int w = tid >> 6;                 // 0..7
  const int wm = w >> 2, wn = w & 3;      // 2 x 4
  const int wr = wm * 128, wc = wn * 64;

  f4 acc[8][4] = {};
  const int NT = K >> 5;

  // thread t stages chunks j = t, t+512 of each 256x32 tile: row j>>2,
  // slot j&3 (LDS linear); global source chunk pre-swizzled by (row>>1)&3.
  #define STAGE3(tt)                                                            \
    {                                                                           \
      const int kk = (tt) << 5;                                                 \
      const int bsel_ = (tt) & 3;                                               \
      const int r_ = tid >> 2;                                                  \
      const int cs_ = ((tid & 3) ^ ((r_ >> 1) & 3)) * 8;                        \
      gload_lds16(Ap + (size_t)(m0 + r_) * lda + kk + cs_,                      \
                  &As[bsel_][tid * 8]);                                         \
      gload_lds16(Ap + (size_t)(m0 + 128 + r_) * lda + kk + cs_,                \
                  &As[bsel_][(tid + 512) * 8]);                                 \
      gload_lds16(Bp + (size_t)(n0 + r_) * ldb + kk + cs_,                      \
                  &Bs[bsel_][tid * 8]);                                         \
      gload_lds16(Bp + (size_t)(n0 + 128 + r_) * ldb + kk + cs_,                \
                  &Bs[bsel_][(tid + 512) * 8]);                                 \
    }

  STAGE3(0);
  if (NT > 1) STAGE3(1);
  if (NT > 2) STAGE3(2);

  // fragment-read swizzle: (ar>>1)&3 == (tl>>1)&3 for all our row offsets
  const int rc = (g ^ ((tl >> 1) & 3)) * 8;

  for (int t = 0; t < NT; ++t) {
    if (t + 2 < NT)      asm volatile("s_waitcnt vmcnt(8)" ::: "memory");
    else if (t + 1 < NT) asm volatile("s_waitcnt vmcnt(4)" ::: "memory");
    else                 asm volatile("s_waitcnt vmcnt(0)" ::: "memory");
    __builtin_amdgcn_sched_barrier(0);
    __builtin_amdgcn_s_barrier();          // tile t visible; slot t-1 reads done
    __builtin_amdgcn_sched_barrier(0);

    if (t + 3 < NT) STAGE3(t + 3);         // -> slot (t+3)%4 == (t-1)%4, safe

    const int bsel = t & 3;
    bf8 af[8], bfr[4];
    #pragma unroll
    for (int i = 0; i < 8; ++i)
      af[i] = *(const bf8*)&As[bsel][(wr + i * 16 + tl) * 32 + rc];
    #pragma unroll
    for (int i = 0; i < 4; ++i)
      bfr[i] = *(const bf8*)&Bs[bsel][(wc + i * 16 + tl) * 32 + rc];

    __builtin_amdgcn_s_setprio(1);
    #pragma unroll
    for (int mi = 0; mi < 8; ++mi)
      #pragma unroll
      for (int ni = 0; ni < 4; ++ni)
        acc[mi][ni] = __builtin_amdgcn_mfma_f32_16x16x32_bf16(af[mi], bfr[ni], acc[mi][ni], 0, 0, 0);
    __builtin_amdgcn_s_setprio(0);
  }
  #undef STAGE3

  #pragma unroll
  for (int mi = 0; mi < 8; ++mi) {
    #pragma unroll
    for (int r = 0; r < 4; ++r) {
      const int row = m0 + wr + mi * 16 + g * 4 + r;
      #pragma unroll
      for (int ni = 0; ni < 4; ++ni) {
        const int col = n0 + wc + ni * 16 + tl;
        const float v = acc[mi][ni][r];
        if constexpr (OF32) ((float*)Cp)[(size_t)row * ldc + col] = v;
        else                ((uint16_t*)Cp)[(size_t)row * ldc + col] = f2bf(v);
      }
    }
  }
}

// ---------- RoPE (in-place on bf16, pairs (d, d+64)) ----------
__global__ __launch_bounds__(256)
void eagle3_rope(uint16_t* __restrict__ x, const float* __restrict__ cs,
                 const float* __restrict__ sn, int nh, int rowlen, int total)
{
  int id = blockIdx.x * 256 + threadIdx.x;
  if (id >= total) return;
  int d = id & 63;
  int t = id >> 6;
  int head = t & (nh - 1);
  int row = t / nh;
  int s = row & 2047;
  size_t base = (size_t)row * rowlen + head * 128;
  float c = cs[s * 128 + d], si = sn[s * 128 + d];
  float x1 = bf2f(x[base + d]), x2 = bf2f(x[base + d + 64]);
  x[base + d]      = f2bf(x1 * c - x2 * si);
  x[base + d + 64] = f2bf(x2 * c + x1 * si);
}

// ---------- V transpose: [b,t,h,d] -> [b,h,d,t] ----------
__global__ __launch_bounds__(256)
void eagle3_vtrans(const uint16_t* __restrict__ V, uint16_t* __restrict__ Vt)
{
  __shared__ uint16_t T[64 * 136];
  const int tid = threadIdx.x;
  const int t0 = blockIdx.x * 64;
  const int bh = blockIdx.y;
  const int b = bh >> 3, h = bh & 7;
  {
    const int r = tid >> 2, c0 = (tid & 3) * 32;
    const uint16_t* src = V + (size_t)(b * 2048 + t0 + r) * 1024 + h * 128 + c0;
    #pragma unroll
    for (int j = 0; j < 4; ++j)
      *(bf8*)&T[r * 136 + c0 + j * 8] = *(const bf8*)(src + j * 8);
  }
  __syncthreads();
  {
    const int d = tid >> 1, tc = (tid & 1) * 32;
    uint16_t* dst = Vt + ((size_t)bh * 128 + d) * 2048 + t0 + tc;
    #pragma unroll
    for (int cc = 0; cc < 4; ++cc) {
      bf8 v;
      #pragma unroll
      for (int j = 0; j < 8; ++j) v[j] = T[(tc + cc * 8 + j) * 136 + d];
      *(bf8*)&dst[cc * 8] = v;
    }
  }
}

// ---------- causal GQA flash attention v5 ----------
// v4 + : raw-score domain with exp2 (scale*log2e folded), interior-tile mask
// skip, P->bf16 via v_cvt_pk_bf16_f32, and softmax denominator accumulated by
// MFMA against a ones-column B-fragment (l = acc col 0, rescaled with O; the
// 16 sum-shuffles per tile are gone -> 4 shfl once at the end).
__global__ __launch_bounds__(256, 2)
void eagle3_flash5(const uint16_t* __restrict__ Q, const uint16_t* __restrict__ Kt,
                   const uint16_t* __restrict__ Vt, uint16_t* __restrict__ O)
{
  __shared__ __align__(16) uint16_t Ks[2][64 * 128];
  __shared__ __align__(16) uint16_t Vs[2][128 * 64];
  __shared__ __align__(16) uint16_t Pl[4][16 * 72];

  const int tid = threadIdx.x, lane = tid & 63, w = tid >> 6;
  const int tl = lane & 15, g = lane >> 4;

  const int bid = (int)blockIdx.x + ((int)blockIdx.y << 5) + ((int)blockIdx.z << 10);
  const int xcd = bid & 7, idx = bid >> 3;
  const int grp = xcd * 2 + (idx >> 7);
  const int j   = idx & 127;
  const int b = grp >> 3, hkv = grp & 7;
  const int hq = hkv * 4 + (j & 3);
  const int qt = 31 - (j >> 2);
  const int qrow0 = qt * 64 + w * 16;
  const int ntb = qt + 1;

  bf8 qf[4];
  {
    const uint16_t* qp = Q + ((size_t)(b * 2048 + qrow0 + tl)) * 4096 + hq * 128 + g * 8;
    #pragma unroll
    for (int kb = 0; kb < 4; ++kb) qf[kb] = *(const bf8*)(qp + kb * 32);
  }

  const uint16_t* Kbase = Kt + (size_t)b * 2048 * 1024 + hkv * 128;
  const uint16_t* Vtb   = Vt + ((size_t)(b * 8 + hkv) * 128) * 2048;

  // ones B-fragment: B[k][0] = 1.0 for all k -> MFMA computes row-sums in col 0
  bf8 onesf = {};
  if (tl == 0) {
    #pragma unroll
    for (int q8 = 0; q8 < 8; ++q8) onesf[q8] = (short)0x3F80;
  }

  f4 acc[8] = {};
  f4 accl = {};                               // softmax denominators (col 0)
  float rm[4] = {-3e38f, -3e38f, -3e38f, -3e38f};
  const float KS = 0.1275174f;                // log2(e)/sqrt(128)

  #define STAGE_TILE(buf, t0s)                                                   \
    {                                                                            \
      _Pragma("unroll")                                                          \
      for (int i = 0; i < 4; ++i) {                                              \
        const int f = i * 256 + tid;                                             \
        const int r = f >> 4, c = f & 15;                                        \
        gload_lds16(Kbase + (size_t)((t0s) + r) * 1024 + ((c ^ (r & 7)) * 8),    \
                    &Ks[buf][(i * 256 + w * 64) * 8]);                           \
      }                                                                          \
      _Pragma("unroll")                                                          \
      for (int i = 0; i < 4; ++i) {                                              \
        const int f = i * 256 + tid;                                             \
        const int d = f >> 3, c = f & 7;                                         \
        gload_lds16(Vtb + (size_t)d * 2048 + (t0s) + ((c ^ (d & 7)) * 8),        \
                    &Vs[buf][(i * 256 + w * 64) * 8]);                           \
      }                                                                          \
    }

  STAGE_TILE(0, 0);

  for (int tb = 0; tb < ntb; ++tb) {
    const int cur = tb & 1;
    const int t0 = tb * 64;

    if (tb + 1 < ntb) {
      STAGE_TILE(cur ^ 1, t0 + 64);
      asm volatile("s_waitcnt vmcnt(8)" ::: "memory");
    } else {
      asm volatile("s_waitcnt vmcnt(0)" ::: "memory");
    }
    __builtin_amdgcn_sched_barrier(0);
    __builtin_amdgcn_s_barrier();

    // -- QK^T (raw scores) --
    f4 s[4] = {};
    __builtin_amdgcn_s_setprio(1);
    #pragma unroll
    for (int cf = 0; cf < 4; ++cf) {
      #pragma unroll
      for (int kb = 0; kb < 4; ++kb) {
        const bf8 kf = *(const bf8*)&Ks[cur][(cf * 16 + tl) * 128 +
                                            (((kb * 4 + g) ^ (tl & 7)) * 8)];
        s[cf] = __builtin_amdgcn_mfma_f32_16x16x32_bf16(qf[kb], kf, s[cf], 0, 0, 0);
      }
    }
    __builtin_amdgcn_s_setprio(0);

    // -- online softmax (raw domain; mask only on the edge tile) --
    const bool edge = (tb == ntb - 1);
    float p[4][4];
    #pragma unroll
    for (int r = 0; r < 4; ++r) {
      float v[4];
      #pragma unroll
      for (int cf = 0; cf < 4; ++cf) v[cf] = s[cf][r];
      if (edge) {
        const int qg = qrow0 + g * 4 + r;
        #pragma unroll
        for (int cf = 0; cf < 4; ++cf)
          if (t0 + cf * 16 + tl > qg) v[cf] = -3e38f;
      }
      float mx = fmaxf(fmaxf(v[0], v[1]), fmaxf(v[2], v[3]));
      mx = fmaxf(mx, __shfl_xor(mx, 1));
      mx = fmaxf(mx, __shfl_xor(mx, 2));
      mx = fmaxf(mx, __shfl_xor(mx, 4));
      mx = fmaxf(mx, __shfl_xor(mx, 8));
      if (mx > rm[r]) {                        // rescale only when max grows
        const float corr = exp2f((rm[r] - mx) * KS);
        #pragma unroll
        for (int df = 0; df < 8; ++df) acc[df][r] *= corr;
        accl[r] *= corr;
        rm[r] = mx;
      }
      #pragma unroll
      for (int cf = 0; cf < 4; ++cf) p[r][cf] = exp2f((v[cf] - rm[r]) * KS);
    }

    // -- P -> LDS via cvt_pk (lo=src0), re-read as A-fragments --
    #pragma unroll
    for (int r = 0; r < 4; ++r) {
      const uint32_t pk0 = cvtpk(p[r][0], p[r][1]);
      const uint32_t pk1 = cvtpk(p[r][2], p[r][3]);
      uint16_t* Pw = &Pl[w][(g * 4 + r) * 72 + tl];
      Pw[0]  = (uint16_t)pk0;
      Pw[16] = (uint16_t)(pk0 >> 16);
      Pw[32] = (uint16_t)pk1;
      Pw[48] = (uint16_t)(pk1 >> 16);
    }
    const bf8 pf0 = *(const bf8*)&Pl[w][tl * 72 + g * 8];
    const bf8 pf1 = *(const bf8*)&Pl[w][tl * 72 + 32 + g * 8];

    // -- PV + denominator MFMAs --
    __builtin_amdgcn_s_setprio(1);
    accl = __builtin_amdgcn_mfma_f32_16x16x32_bf16(pf0, onesf, accl, 0, 0, 0);
    accl = __builtin_amdgcn_mfma_f32_16x16x32_bf16(pf1, onesf, accl, 0, 0, 0);
    #pragma unroll
    for (int df = 0; df < 8; ++df) {
      const int vrow = (df * 16 + tl) * 64;
      const bf8 v0 = *(const bf8*)&Vs[cur][vrow + ((g ^ (tl & 7)) * 8)];
      const bf8 v1 = *(const bf8*)&Vs[cur][vrow + (((4 + g) ^ (tl & 7)) * 8)];
      acc[df] = __builtin_amdgcn_mfma_f32_16x16x32_bf16(pf0, v0, acc[df], 0, 0, 0);
      acc[df] = __builtin_amdgcn_mfma_f32_16x16x32_bf16(pf1, v1, acc[df], 0, 0, 0);
    }
    __builtin_amdgcn_s_setprio(0);

    __builtin_amdgcn_s_barrier();
  }
  #undef STAGE_TILE

  // -- normalize (l broadcast from col-0 lane of each 16-lane group) + store --
  #pragma unroll
  for (int r = 0; r < 4; ++r) {
    const float l = __shfl(accl[r], lane & 48);
    const float inv = 1.0f / l;
    const size_t ob = ((size_t)(b * 2048 + qrow0 + g * 4 + r)) * 4096 + hq * 128 + tl;
    #pragma unroll
    for (int df = 0; df < 8; ++df)
      O[ob + df * 16] = f2bf(acc[df][r] * inv);
  }
}

// ---------- launch ----------
extern "C" void kernel_launch(void* const* d_in, const int* in_sizes, int n_in,
                              void* d_out, int out_size, void* d_ws, size_t ws_size,
                              hipStream_t stream) {
  const float* hs   = (const float*)d_in[0];
  const float* cosT = (const float*)d_in[2];
  const float* sinT = (const float*)d_in[3];
  const float* Wq   = (const float*)d_in[4];
  const float* Wk   = (const float*)d_in[5];
  const float* Wv   = (const float*)d_in[6];
  const float* Wo   = (const float*)d_in[7];

  char* ws = (char*)d_ws;
  uint16_t* qb    = (uint16_t*)(ws);
  uint16_t* kbuf  = (uint16_t*)(ws + 33554432);
  uint16_t* vbuf  = (uint16_t*)(ws + 41943040);
  uint16_t* whalf = (uint16_t*)(ws + 50331648);
  uint16_t* vt    = (uint16_t*)(ws + 75497472);
  uint16_t* ctx   = (uint16_t*)(ws + 41943040);
  uint16_t* hsb   = (uint16_t*)d_out;
  uint16_t* wobf  = qb;

  const dim3 blk(256);
  const bool fullq = (ws_size >= (size_t)117440512);   // 112 MiB

  // 1) hs f32 -> bf16 (once)
  eagle3_cvt<<<dim3(2048), blk, 0, stream>>>(hs, hsb, 4194304);

  // 2) Q projection
  if (fullq) {
    eagle3_cvt<<<dim3(2048), blk, 0, stream>>>(Wq, whalf, 4194304);
    eagle3_gemm3<false><<<dim3(16, 16), dim3(512), 0, stream>>>(
        hsb, whalf, (void*)qb, 8192, 8192, 8192, 4096);
  } else {
    eagle3_cvt<<<dim3(2048), blk, 0, stream>>>(Wq, whalf, 2097152);
    eagle3_gemm2<false><<<dim3(16, 32), blk, 0, stream>>>(
        hsb, whalf, (void*)qb, 8192, 8192, 8192, 4096);
    eagle3_cvt<<<dim3(2048), blk, 0, stream>>>(Wq + 16777216, whalf, 2097152);
    eagle3_gemm2<false><<<dim3(16, 32), blk, 0, stream>>>(
        hsb, whalf, (void*)(qb + 2048), 8192, 8192, 8192, 4096);
  }

  // 3) K and V projections
  eagle3_cvt<<<dim3(2048), blk, 0, stream>>>(Wk, whalf, 1048576);
  eagle3_gemm2<false><<<dim3(8, 32), blk, 0, stream>>>(
      hsb, whalf, (void*)kbuf, 8192, 8192, 8192, 1024);
  eagle3_cvt<<<dim3(2048), blk, 0, stream>>>(Wv, whalf, 1048576);
  eagle3_gemm2<false><<<dim3(8, 32), blk, 0, stream>>>(
      hsb, whalf, (void*)vbuf, 8192, 8192, 8192, 1024);

  // 4) RoPE + V transpose
  eagle3_rope<<<dim3(32768), blk, 0, stream>>>(qb, cosT, sinT, 32, 4096, 8388608);
  eagle3_rope<<<dim3(8192), blk, 0, stream>>>(kbuf, cosT, sinT, 8, 1024, 2097152);
  eagle3_vtrans<<<dim3(32, 16), blk, 0, stream>>>(vbuf, vt);

  // 5) causal GQA flash attention -> ctx
  eagle3_flash5<<<dim3(32, 32, 2), blk, 0, stream>>>(qb, kbuf, vt, ctx);

  // 6) output projection: out = ctx * Wo^T (f32 out over dead hsb)
  eagle3_cvt<<<dim3(2048), blk, 0, stream>>>(Wo, wobf, 2097152);
  eagle3_gemm3<true><<<dim3(16, 16), dim3(512), 0, stream>>>(
      ctx, wobf, d_out, 4096, 4096, 4096, 4096);
}